// Round 10
// baseline (465.870 us; speedup 1.0000x reference)
//
#include <hip/hip_runtime.h>
#include <cstddef>
#include <cstdint>

#define HIDDEN    1024
#define OUTD      1024
#define NUM_TABLE 64
#define CODE_LEN  10
#define TABLE_SZ  1024
#define TOTAL_DIM 640

#define TAU   3e-3f
#define FCAP  131072u

typedef float    fx4   __attribute__((ext_vector_type(4)));
typedef ushort   ux4   __attribute__((ext_vector_type(4)));
typedef _Float16 f16x8 __attribute__((ext_vector_type(8)));
typedef float    f32x4 __attribute__((ext_vector_type(4)));

// async global->LDS, 16B per lane; LDS dest is wave-uniform base + lane*16
#define GLOAD16(g, l)                                                        \
    __builtin_amdgcn_global_load_lds(                                        \
        (const __attribute__((address_space(1))) void*)(g),                  \
        (__attribute__((address_space(3))) void*)(l), 16, 0, 0)

static __device__ __forceinline__ ushort f2bf(float f) {   // RNE, for tables
    uint32_t u = __float_as_uint(f);
    return (ushort)((u + 0x7FFFu + ((u >> 16) & 1u)) >> 16);
}

// ---------------- convert x: [N][1024] f32 -> fp16 (same layout) ----------------
__global__ __launch_bounds__(256)
void cvt_x(const float* __restrict__ x, _Float16* __restrict__ xf, int n8)
{
    const fx4* xp = (const fx4*)x;
    int stride = gridDim.x * 256;
    for (int i = blockIdx.x * 256 + threadIdx.x; i < n8; i += stride) {
        fx4 v0 = xp[i * 2], v1 = xp[i * 2 + 1];
        f16x8 h;
        h[0] = (_Float16)v0.x; h[1] = (_Float16)v0.y;
        h[2] = (_Float16)v0.z; h[3] = (_Float16)v0.w;
        h[4] = (_Float16)v1.x; h[5] = (_Float16)v1.y;
        h[6] = (_Float16)v1.z; h[7] = (_Float16)v1.w;
        *(f16x8*)&xf[(size_t)i * 8] = h;
    }
}

// ---------------- convert + transpose W: [1024][640] f32 -> wf [640][1024] fp16 --
__global__ __launch_bounds__(256)
void cvt_wt(const float* __restrict__ W, _Float16* __restrict__ wf)
{
    __shared__ float t[32][33];
    const int d0 = blockIdx.x * 32, k0 = blockIdx.y * 32;
    const int lx = threadIdx.x & 31, ly = threadIdx.x >> 5;   // 32 x 8
    #pragma unroll
    for (int i = 0; i < 32; i += 8)
        t[ly + i][lx] = W[(size_t)(k0 + ly + i) * TOTAL_DIM + d0 + lx];
    __syncthreads();
    #pragma unroll
    for (int i = 0; i < 32; i += 8)
        wf[(size_t)(d0 + ly + i) * HIDDEN + k0 + lx] = (_Float16)t[lx][ly + i];
}

// ---------------- fused: fp16 MFMA GEMM (gload_lds) + table convert ------------
// GEMM blocks 0..319: z = x @ W + b, single fp16 product; 128x128 tile, BK=32.
// A/B tiles linear [128][32] fp16, staged via global_load_lds width=16.
// Bank fix: pre-swizzled global source slot + XOR on ds_read (rule 21).
// Convert blocks 320..1343: fp32 tables -> bf16 btab, grid-stride, nt loads.
#define GBM 128
#define GBN 128
#define GBK 32
#define GEMM_MB (8192 / GBM)              // 64
#define GEMM_NB (TOTAL_DIM / GBN)         // 5
#define GEMM_BLKS (GEMM_MB * GEMM_NB)     // 320
#define CONV_BLKS 1024

__global__ __launch_bounds__(256)
void gemm_convert(const _Float16* __restrict__ xf, const _Float16* __restrict__ wf,
                  const float* __restrict__ bproj, float* __restrict__ z,
                  const float* __restrict__ tables, ushort* __restrict__ btab)
{
    __shared__ _Float16 Asm[GBM * GBK];
    __shared__ _Float16 Bsm[GBN * GBK];

    const int gb  = blockIdx.x;
    const int tid = threadIdx.x;

    if (gb >= GEMM_BLKS) {
        // ---- convert path: grid-stride, nt loads ----
        const int cb = gb - GEMM_BLKS;                 // 0..1023
        const int n4 = NUM_TABLE * TABLE_SZ * (OUTD / 4);
        const fx4* tp = (const fx4*)tables;
        const int stride = CONV_BLKS * 256;
        for (int i = cb * 256 + tid; i < n4; i += stride) {
            fx4 v = __builtin_nontemporal_load(&tp[i]);
            ux4 u;
            u.x = f2bf(v.x); u.y = f2bf(v.y); u.z = f2bf(v.z); u.w = f2bf(v.w);
            *(ux4*)&btab[(size_t)i * 4] = u;
        }
        return;
    }

    // ---- GEMM path ----
    const int lane = tid & 63, wid = tid >> 6;
    const int wr = wid >> 1, wc = wid & 1;             // 2x2 wave grid
    const int brow = (gb % GEMM_MB) * GBM;
    const int bcol = (gb / GEMM_MB) * GBN;
    const int fr = lane & 15, fq = lane >> 4;

    // staging lane geometry: chunk covers rows chunk*16..+15, row = 32 f16 = 64 B
    const int lrow  = lane >> 2;                       // 0..15
    const int lslot = (lane & 3) ^ (lrow & 3);         // pre-swizzled source slot
    const int lcol  = lslot * 8;                       // f16 offset in row

    f32x4 acc[4][4] = {};

    for (int k0 = 0; k0 < HIDDEN; k0 += GBK) {
        #pragma unroll
        for (int j = 0; j < 2; ++j) {
            const int chunk = wid * 2 + j;             // 0..7 (wave-uniform)
            const int r     = chunk * 16 + lrow;       // 0..127
            GLOAD16(xf + (size_t)(brow + r) * HIDDEN + k0 + lcol, &Asm[chunk * 512]);
            GLOAD16(wf + (size_t)(bcol + r) * HIDDEN + k0 + lcol, &Bsm[chunk * 512]);
        }
        __syncthreads();

        f16x8 a[4], b[4];
        #pragma unroll
        for (int m = 0; m < 4; ++m) {
            int r = wr * 64 + m * 16 + fr;
            a[m] = *(const f16x8*)&Asm[r * 32 + ((fq ^ (r & 3)) * 8)];
        }
        #pragma unroll
        for (int n = 0; n < 4; ++n) {
            int r = wc * 64 + n * 16 + fr;
            b[n] = *(const f16x8*)&Bsm[r * 32 + ((fq ^ (r & 3)) * 8)];
        }
        #pragma unroll
        for (int m = 0; m < 4; ++m)
            #pragma unroll
            for (int n = 0; n < 4; ++n)
                acc[m][n] = __builtin_amdgcn_mfma_f32_16x16x32_f16(a[m], b[n], acc[m][n], 0, 0, 0);
        __syncthreads();
    }

    // epilogue: +bias; C/D mapping col=lane&15, row=(lane>>4)*4+reg
    #pragma unroll
    for (int n = 0; n < 4; ++n) {
        int col = bcol + wc * 64 + n * 16 + fr;
        float bb = bproj[col];
        #pragma unroll
        for (int m = 0; m < 4; ++m) {
            int rbase = brow + wr * 64 + m * 16 + fq * 4;
            #pragma unroll
            for (int j = 0; j < 4; ++j)
                z[(size_t)(rbase + j) * TOTAL_DIM + col] = acc[m][n][j] + bb;
        }
    }
}

// ---------------- code / score + near-zero flagging (sign in flag bit31) -------
__global__ __launch_bounds__(256)
void code_score2(const float* __restrict__ z, int* __restrict__ code,
                 float* __restrict__ score, uint32_t* __restrict__ flags,
                 uint32_t* __restrict__ cnt, int NT)
{
    int idx = blockIdx.x * 256 + threadIdx.x;
    if (idx >= NT) return;
    int n = idx >> 6;
    int t = idx & 63;
    const float* zp = z + (size_t)n * TOTAL_DIM + t * CODE_LEN;
    float s = 1.0f;
    int   c = 0;
    #pragma unroll
    for (int i = 0; i < CODE_LEN; ++i) {
        float v = zp[i];
        if (fabsf(v) < TAU) {                       // sign uncertain under fp16
            uint32_t slot = atomicAdd(cnt, 1u);
            if (slot < FCAP) {
                uint32_t nd = (uint32_t)(n * TOTAL_DIM + t * CODE_LEN + i);
                flags[slot] = nd | (v > 0.0f ? 0x80000000u : 0u);
            }
        }
        s *= 0.5f * (1.0f + tanhf(fabsf(v)));
        c |= (v > 0.0f) ? (1 << i) : 0;
    }
    code[idx]  = c;
    score[idx] = s;
}

// ---------------- exact fp32 recompute of flagged z; fix code bits ----------------
__global__ __launch_bounds__(256)
void fixz(const float* __restrict__ x, const float* __restrict__ W,
          const float* __restrict__ bproj, int* __restrict__ code,
          const uint32_t* __restrict__ flags, const uint32_t* __restrict__ cnt)
{
    const int lane = threadIdx.x & 63;
    const int gw   = (blockIdx.x * 256 + threadIdx.x) >> 6;
    const int nw   = (gridDim.x * 256) >> 6;
    uint32_t count = *cnt;
    if (count > FCAP) count = FCAP;

    for (uint32_t f = gw; f < count; f += nw) {
        uint32_t fl = flags[f];
        uint32_t e  = fl & 0x7FFFFFFFu;
        int oldpos  = (int)(fl >> 31);
        int n = e / TOTAL_DIM, d = e % TOTAL_DIM;
        const float* xr = x + (size_t)n * HIDDEN;
        float p = 0.0f;
        #pragma unroll
        for (int j = 0; j < 16; ++j) {
            int k = lane + j * 64;
            p = fmaf(xr[k], W[(size_t)k * TOTAL_DIM + d], p);
        }
        #pragma unroll
        for (int off = 32; off; off >>= 1) p += __shfl_xor(p, off);
        float v = p + bproj[d];
        if (lane == 0) {
            if ((v > 0.0f) != (oldpos != 0)) {
                int t = d / CODE_LEN, i = d % CODE_LEN;
                atomicXor(&code[n * NUM_TABLE + t], 1 << i);
            }
        }
    }
}

// ---------------- gather + weighted sum (bf16 tables, full 1024-col rows) --------
__global__ __launch_bounds__(256)
void gather_sum_bf16(const ushort* __restrict__ btab, const float* __restrict__ bias,
                     const int* __restrict__ code, const float* __restrict__ score,
                     float* __restrict__ out)
{
    __shared__ int   sc[NUM_TABLE];
    __shared__ float sw[NUM_TABLE];

    const int n   = blockIdx.x;
    const int tid = threadIdx.x;

    if (tid < NUM_TABLE) {
        sc[tid] = code[n * NUM_TABLE + tid];
        sw[tid] = score[n * NUM_TABLE + tid];
    }
    __syncthreads();

    float4 acc = *(const float4*)&bias[tid * 4];

    #pragma unroll 8
    for (int t = 0; t < NUM_TABLE; ++t) {
        const ux4 v = *(const ux4*)&btab[((size_t)(t * TABLE_SZ + sc[t])) * OUTD + tid * 4];
        float w = sw[t];
        acc.x += w * __uint_as_float((uint32_t)v.x << 16);
        acc.y += w * __uint_as_float((uint32_t)v.y << 16);
        acc.z += w * __uint_as_float((uint32_t)v.z << 16);
        acc.w += w * __uint_as_float((uint32_t)v.w << 16);
    }

    *(float4*)&out[(size_t)n * OUTD + tid * 4] = acc;
}

// ---------------- fallback path (ws too small): fp32 vector GEMM + f32 gather ----
#define BM 64
#define BN 64
#define BK 32
__global__ __launch_bounds__(256)
void gemm_proj(const float* __restrict__ x, const float* __restrict__ W,
               const float* __restrict__ bproj, float* __restrict__ z)
{
    __shared__ float As[BK][BM + 4];
    __shared__ float Bs[BK][BN];
    const int tid  = threadIdx.x;
    const int brow = blockIdx.x * BM;
    const int bcol = blockIdx.y * BN;
    const int tr   = tid >> 4;
    const int tc   = tid & 15;
    float acc[4][4] = {};
    for (int k0 = 0; k0 < HIDDEN; k0 += BK) {
        #pragma unroll
        for (int i = 0; i < 2; ++i) {
            int lin = tid + i * 256;
            int r = lin >> 3, c8 = lin & 7;
            float4 a = *(const float4*)&x[(size_t)(brow + r) * HIDDEN + k0 + c8 * 4];
            As[c8 * 4 + 0][r] = a.x; As[c8 * 4 + 1][r] = a.y;
            As[c8 * 4 + 2][r] = a.z; As[c8 * 4 + 3][r] = a.w;
        }
        #pragma unroll
        for (int i = 0; i < 2; ++i) {
            int lin = tid + i * 256;
            int kk = lin >> 4, m4 = lin & 15;
            *(float4*)&Bs[kk][m4 * 4] =
                *(const float4*)&W[(size_t)(k0 + kk) * TOTAL_DIM + bcol + m4 * 4];
        }
        __syncthreads();
        #pragma unroll
        for (int kk = 0; kk < BK; ++kk) {
            float4 a = *(const float4*)&As[kk][tr * 4];
            float4 b = *(const float4*)&Bs[kk][tc * 4];
            acc[0][0] += a.x * b.x; acc[0][1] += a.x * b.y; acc[0][2] += a.x * b.z; acc[0][3] += a.x * b.w;
            acc[1][0] += a.y * b.x; acc[1][1] += a.y * b.y; acc[1][2] += a.y * b.z; acc[1][3] += a.y * b.w;
            acc[2][0] += a.z * b.x; acc[2][1] += a.z * b.y; acc[2][2] += a.z * b.z; acc[2][3] += a.z * b.w;
            acc[3][0] += a.w * b.x; acc[3][1] += a.w * b.y; acc[3][2] += a.w * b.z; acc[3][3] += a.w * b.w;
        }
        __syncthreads();
    }
    float4 bb = *(const float4*)&bproj[bcol + tc * 4];
    #pragma unroll
    for (int i = 0; i < 4; ++i) {
        int r = brow + tr * 4 + i;
        float4 o = {acc[i][0] + bb.x, acc[i][1] + bb.y, acc[i][2] + bb.z, acc[i][3] + bb.w};
        *(float4*)&z[(size_t)r * TOTAL_DIM + bcol + tc * 4] = o;
    }
}

__global__ __launch_bounds__(256)
void code_score(const float* __restrict__ z, int* __restrict__ code,
                float* __restrict__ score, int NT)
{
    int idx = blockIdx.x * 256 + threadIdx.x;
    if (idx >= NT) return;
    int n = idx >> 6, t = idx & 63;
    const float* zp = z + (size_t)n * TOTAL_DIM + t * CODE_LEN;
    float s = 1.0f; int c = 0;
    #pragma unroll
    for (int i = 0; i < CODE_LEN; ++i) {
        float v = zp[i];
        s *= 0.5f * (1.0f + tanhf(fabsf(v)));
        c |= (v > 0.0f) ? (1 << i) : 0;
    }
    code[idx] = c; score[idx] = s;
}

__global__ __launch_bounds__(256)
void gather_sum_f32(const float* __restrict__ tables, const float* __restrict__ bias,
                    const int* __restrict__ code, const float* __restrict__ score,
                    float* __restrict__ out)
{
    __shared__ int   sc[NUM_TABLE];
    __shared__ float sw[NUM_TABLE];
    const int n = blockIdx.x, tid = threadIdx.x;
    if (tid < NUM_TABLE) {
        sc[tid] = code[n * NUM_TABLE + tid];
        sw[tid] = score[n * NUM_TABLE + tid];
    }
    __syncthreads();
    float4 acc = *(const float4*)&bias[tid * 4];
    #pragma unroll 4
    for (int t = 0; t < NUM_TABLE; ++t) {
        const float* row = tables + ((size_t)(t * TABLE_SZ + sc[t])) * OUTD;
        float4 v = *(const float4*)&row[tid * 4];
        float w = sw[t];
        acc.x += v.x * w; acc.y += v.y * w; acc.z += v.z * w; acc.w += v.w * w;
    }
    *(float4*)&out[(size_t)n * OUTD + tid * 4] = acc;
}

extern "C" void kernel_launch(void* const* d_in, const int* in_sizes, int n_in,
                              void* d_out, int out_size, void* d_ws, size_t ws_size,
                              hipStream_t stream) {
    const float* x      = (const float*)d_in[0];
    const float* W      = (const float*)d_in[1];
    const float* bproj  = (const float*)d_in[2];
    const float* tables = (const float*)d_in[3];
    const float* bias   = (const float*)d_in[4];
    float* out = (float*)d_out;

    const int N = in_sizes[0] / HIDDEN;           // 8192

    // ws: z | code | score | wf | xf | flags | cnt | btab
    char* ws = (char*)d_ws;
    size_t off_z     = 0;
    size_t off_code  = off_z     + (size_t)N * TOTAL_DIM * sizeof(float);
    size_t off_score = off_code  + (size_t)N * NUM_TABLE * sizeof(int);
    size_t off_wf    = off_score + (size_t)N * NUM_TABLE * sizeof(float);
    size_t off_xf    = off_wf    + (size_t)TOTAL_DIM * HIDDEN * sizeof(_Float16);
    size_t off_flags = off_xf    + (size_t)N * HIDDEN * sizeof(_Float16);
    size_t off_cnt   = off_flags + (size_t)FCAP * sizeof(uint32_t);
    size_t off_btab  = (off_cnt + 4 + 255) & ~(size_t)255;
    size_t tab_elems = (size_t)NUM_TABLE * TABLE_SZ * OUTD;
    size_t need      = off_btab + tab_elems * sizeof(ushort);

    float*    z     = (float*)(ws + off_z);
    int*      code  = (int*)(ws + off_code);
    float*    score = (float*)(ws + off_score);
    _Float16* wf    = (_Float16*)(ws + off_wf);
    _Float16* xf    = (_Float16*)(ws + off_xf);
    uint32_t* flags = (uint32_t*)(ws + off_flags);
    uint32_t* cnt   = (uint32_t*)(ws + off_cnt);
    ushort*   btab  = (ushort*)(ws + off_btab);

    int NT = N * NUM_TABLE;

    if (ws_size >= need) {
        cvt_x<<<1024, 256, 0, stream>>>(x, xf, N * HIDDEN / 8);
        dim3 gw(TOTAL_DIM / 32, HIDDEN / 32);
        cvt_wt<<<gw, 256, 0, stream>>>(W, wf);
        (void)hipMemsetAsync(cnt, 0, 4, stream);

        gemm_convert<<<GEMM_BLKS + CONV_BLKS, 256, 0, stream>>>(
            xf, wf, bproj, z, tables, btab);

        code_score2<<<(NT + 255) / 256, 256, 0, stream>>>(z, code, score, flags, cnt, NT);
        fixz<<<512, 256, 0, stream>>>(x, W, bproj, code, flags, cnt);

        gather_sum_bf16<<<N, 256, 0, stream>>>(btab, bias, code, score, out);
    } else {
        dim3 g1(N / BM, TOTAL_DIM / BN);
        gemm_proj<<<g1, 256, 0, stream>>>(x, W, bproj, z);
        code_score<<<(NT + 255) / 256, 256, 0, stream>>>(z, code, score, NT);
        gather_sum_f32<<<N, 256, 0, stream>>>(tables, bias, code, score, out);
    }
}

// Round 11
// 458.785 us; speedup vs baseline: 1.0154x; 1.0154x over previous
//
#include <hip/hip_runtime.h>
#include <cstddef>
#include <cstdint>

#define HIDDEN    1024
#define OUTD      1024
#define NUM_TABLE 64
#define CODE_LEN  10
#define TABLE_SZ  1024
#define TOTAL_DIM 640

#define TAU   3e-3f
#define FCAP  131072u

typedef float    fx4   __attribute__((ext_vector_type(4)));
typedef ushort   ux4   __attribute__((ext_vector_type(4)));
typedef _Float16 f16x4 __attribute__((ext_vector_type(4)));
typedef _Float16 f16x8 __attribute__((ext_vector_type(8)));
typedef float    f32x4 __attribute__((ext_vector_type(4)));

static __device__ __forceinline__ ushort f2bf(float f) {   // RNE, for tables
    uint32_t u = __float_as_uint(f);
    return (ushort)((u + 0x7FFFu + ((u >> 16) & 1u)) >> 16);
}

// ---------------- convert + transpose W: [1024][640] f32 -> wf [640][1024] fp16 --
__global__ __launch_bounds__(256)
void cvt_wt(const float* __restrict__ W, _Float16* __restrict__ wf)
{
    __shared__ float t[32][33];
    const int d0 = blockIdx.x * 32, k0 = blockIdx.y * 32;
    const int lx = threadIdx.x & 31, ly = threadIdx.x >> 5;   // 32 x 8
    #pragma unroll
    for (int i = 0; i < 32; i += 8)
        t[ly + i][lx] = W[(size_t)(k0 + ly + i) * TOTAL_DIM + d0 + lx];
    __syncthreads();
    #pragma unroll
    for (int i = 0; i < 32; i += 8)
        wf[(size_t)(d0 + ly + i) * HIDDEN + k0 + lx] = (_Float16)t[lx][ly + i];
}

// ---------------- fp16 MFMA GEMM: z = x @ W + b (round-6 structure) ------------
// x [N,1024] fp32 (converted to fp16 in-register during staging),
// wf [640][1024] fp16. 128x128 tile, BK=32, 4 waves (2x2), 4x4 frags 16x16x32.
#define GBM 128
#define GBN 128
#define GBK 32
#define LDK 40   // padded inner dim (80 B row stride, 16B-aligned, 2-way banks = free)
#define GEMM_MB (8192 / GBM)              // 64
#define GEMM_NB (TOTAL_DIM / GBN)         // 5

__global__ __launch_bounds__(256)
void gemm_f16(const float* __restrict__ x, const _Float16* __restrict__ wf,
              const float* __restrict__ bproj, float* __restrict__ z)
{
    __shared__ _Float16 As[GBM][LDK];
    __shared__ _Float16 Bs[GBN][LDK];

    const int tid  = threadIdx.x;
    const int lane = tid & 63, wid = tid >> 6;
    const int wr = wid >> 1, wc = wid & 1;            // 2x2 wave grid
    const int brow = (blockIdx.x % GEMM_MB) * GBM;
    const int bcol = (blockIdx.x / GEMM_MB) * GBN;
    const int fr = lane & 15, fq = lane >> 4;

    f32x4 acc[4][4] = {};

    for (int k0 = 0; k0 < HIDDEN; k0 += GBK) {
        // stage A: 128x32 fp32 -> fp16 in-register -> LDS
        #pragma unroll
        for (int i = 0; i < 4; ++i) {
            int c = tid + i * 256;                    // 0..1023
            int r = c >> 3, kc = (c & 7) * 4;
            fx4 v = *(const fx4*)&x[(size_t)(brow + r) * HIDDEN + k0 + kc];
            f16x4 h;
            h[0] = (_Float16)v.x; h[1] = (_Float16)v.y;
            h[2] = (_Float16)v.z; h[3] = (_Float16)v.w;
            *(f16x4*)&As[r][kc] = h;
        }
        // stage B^T: 128n x 32k fp16, 16B per thread
        #pragma unroll
        for (int i = 0; i < 2; ++i) {
            int c = tid + i * 256;                    // 0..511
            int nr = c >> 2, kc = (c & 3) * 8;
            *(f16x8*)&Bs[nr][kc] =
                *(const f16x8*)&wf[(size_t)(bcol + nr) * HIDDEN + k0 + kc];
        }
        __syncthreads();

        f16x8 a[4], b[4];
        #pragma unroll
        for (int m = 0; m < 4; ++m)
            a[m] = *(const f16x8*)&As[wr * 64 + m * 16 + fr][fq * 8];
        #pragma unroll
        for (int n = 0; n < 4; ++n)
            b[n] = *(const f16x8*)&Bs[wc * 64 + n * 16 + fr][fq * 8];
        #pragma unroll
        for (int m = 0; m < 4; ++m)
            #pragma unroll
            for (int n = 0; n < 4; ++n)
                acc[m][n] = __builtin_amdgcn_mfma_f32_16x16x32_f16(a[m], b[n], acc[m][n], 0, 0, 0);
        __syncthreads();
    }

    // epilogue: +bias; C/D mapping col=lane&15, row=(lane>>4)*4+reg
    #pragma unroll
    for (int n = 0; n < 4; ++n) {
        int col = bcol + wc * 64 + n * 16 + fr;
        float bb = bproj[col];
        #pragma unroll
        for (int m = 0; m < 4; ++m) {
            int rbase = brow + wr * 64 + m * 16 + fq * 4;
            #pragma unroll
            for (int j = 0; j < 4; ++j)
                z[(size_t)(rbase + j) * TOTAL_DIM + col] = acc[m][n][j] + bb;
        }
    }
}

// ---------------- code / score + near-zero flagging (sign in flag bit31) -------
__global__ __launch_bounds__(256)
void code_score2(const float* __restrict__ z, int* __restrict__ code,
                 float* __restrict__ score, uint32_t* __restrict__ flags,
                 uint32_t* __restrict__ cnt, int NT)
{
    int idx = blockIdx.x * 256 + threadIdx.x;
    if (idx >= NT) return;
    int n = idx >> 6;
    int t = idx & 63;
    const float* zp = z + (size_t)n * TOTAL_DIM + t * CODE_LEN;
    float s = 1.0f;
    int   c = 0;
    #pragma unroll
    for (int i = 0; i < CODE_LEN; ++i) {
        float v = zp[i];
        if (fabsf(v) < TAU) {                       // sign uncertain under fp16
            uint32_t slot = atomicAdd(cnt, 1u);
            if (slot < FCAP) {
                uint32_t nd = (uint32_t)(n * TOTAL_DIM + t * CODE_LEN + i);
                flags[slot] = nd | (v > 0.0f ? 0x80000000u : 0u);
            }
        }
        s *= 0.5f * (1.0f + tanhf(fabsf(v)));
        c |= (v > 0.0f) ? (1 << i) : 0;
    }
    code[idx]  = c;
    score[idx] = s;
}

// ---------------- exact fp32 recompute of flagged z; fix code bits ----------------
__global__ __launch_bounds__(256)
void fixz(const float* __restrict__ x, const float* __restrict__ W,
          const float* __restrict__ bproj, int* __restrict__ code,
          const uint32_t* __restrict__ flags, const uint32_t* __restrict__ cnt)
{
    const int lane = threadIdx.x & 63;
    const int gw   = (blockIdx.x * 256 + threadIdx.x) >> 6;
    const int nw   = (gridDim.x * 256) >> 6;
    uint32_t count = *cnt;
    if (count > FCAP) count = FCAP;

    for (uint32_t f = gw; f < count; f += nw) {
        uint32_t fl = flags[f];
        uint32_t e  = fl & 0x7FFFFFFFu;
        int oldpos  = (int)(fl >> 31);
        int n = e / TOTAL_DIM, d = e % TOTAL_DIM;
        const float* xr = x + (size_t)n * HIDDEN;
        float p = 0.0f;
        #pragma unroll
        for (int j = 0; j < 16; ++j) {
            int k = lane + j * 64;
            p = fmaf(xr[k], W[(size_t)k * TOTAL_DIM + d], p);
        }
        #pragma unroll
        for (int off = 32; off; off >>= 1) p += __shfl_xor(p, off);
        float v = p + bproj[d];
        if (lane == 0) {
            if ((v > 0.0f) != (oldpos != 0)) {
                int t = d / CODE_LEN, i = d % CODE_LEN;
                atomicXor(&code[n * NUM_TABLE + t], 1 << i);
            }
        }
    }
}

// ---------------- fp32 -> bf16 table conversion (RNE), nt loads ----------------
__global__ __launch_bounds__(256)
void convert_tables(const float* __restrict__ t, ushort* __restrict__ o, int n4)
{
    const fx4* tp = (const fx4*)t;
    int stride = gridDim.x * 256;
    for (int i = blockIdx.x * 256 + threadIdx.x; i < n4; i += stride) {
        fx4 v = __builtin_nontemporal_load(&tp[i]);
        ux4 u;
        u.x = f2bf(v.x); u.y = f2bf(v.y); u.z = f2bf(v.z); u.w = f2bf(v.w);
        *(ux4*)&o[(size_t)i * 4] = u;
    }
}

// ---------------- gather + weighted sum (bf16 tables, full 1024-col rows) --------
__global__ __launch_bounds__(256)
void gather_sum_bf16(const ushort* __restrict__ btab, const float* __restrict__ bias,
                     const int* __restrict__ code, const float* __restrict__ score,
                     float* __restrict__ out)
{
    __shared__ int   sc[NUM_TABLE];
    __shared__ float sw[NUM_TABLE];

    const int n   = blockIdx.x;
    const int tid = threadIdx.x;

    if (tid < NUM_TABLE) {
        sc[tid] = code[n * NUM_TABLE + tid];
        sw[tid] = score[n * NUM_TABLE + tid];
    }
    __syncthreads();

    float4 acc = *(const float4*)&bias[tid * 4];

    #pragma unroll 4
    for (int t = 0; t < NUM_TABLE; ++t) {
        const ux4 v = *(const ux4*)&btab[((size_t)(t * TABLE_SZ + sc[t])) * OUTD + tid * 4];
        float w = sw[t];
        acc.x += w * __uint_as_float((uint32_t)v.x << 16);
        acc.y += w * __uint_as_float((uint32_t)v.y << 16);
        acc.z += w * __uint_as_float((uint32_t)v.z << 16);
        acc.w += w * __uint_as_float((uint32_t)v.w << 16);
    }

    *(float4*)&out[(size_t)n * OUTD + tid * 4] = acc;
}

// ---------------- fallback path (ws too small): fp32 vector GEMM + f32 gather ----
#define BM 64
#define BN 64
#define BK 32
__global__ __launch_bounds__(256)
void gemm_proj(const float* __restrict__ x, const float* __restrict__ W,
               const float* __restrict__ bproj, float* __restrict__ z)
{
    __shared__ float As[BK][BM + 4];
    __shared__ float Bs[BK][BN];
    const int tid  = threadIdx.x;
    const int brow = blockIdx.x * BM;
    const int bcol = blockIdx.y * BN;
    const int tr   = tid >> 4;
    const int tc   = tid & 15;
    float acc[4][4] = {};
    for (int k0 = 0; k0 < HIDDEN; k0 += BK) {
        #pragma unroll
        for (int i = 0; i < 2; ++i) {
            int lin = tid + i * 256;
            int r = lin >> 3, c8 = lin & 7;
            float4 a = *(const float4*)&x[(size_t)(brow + r) * HIDDEN + k0 + c8 * 4];
            As[c8 * 4 + 0][r] = a.x; As[c8 * 4 + 1][r] = a.y;
            As[c8 * 4 + 2][r] = a.z; As[c8 * 4 + 3][r] = a.w;
        }
        #pragma unroll
        for (int i = 0; i < 2; ++i) {
            int lin = tid + i * 256;
            int kk = lin >> 4, m4 = lin & 15;
            *(float4*)&Bs[kk][m4 * 4] =
                *(const float4*)&W[(size_t)(k0 + kk) * TOTAL_DIM + bcol + m4 * 4];
        }
        __syncthreads();
        #pragma unroll
        for (int kk = 0; kk < BK; ++kk) {
            float4 a = *(const float4*)&As[kk][tr * 4];
            float4 b = *(const float4*)&Bs[kk][tc * 4];
            acc[0][0] += a.x * b.x; acc[0][1] += a.x * b.y; acc[0][2] += a.x * b.z; acc[0][3] += a.x * b.w;
            acc[1][0] += a.y * b.x; acc[1][1] += a.y * b.y; acc[1][2] += a.y * b.z; acc[1][3] += a.y * b.w;
            acc[2][0] += a.z * b.x; acc[2][1] += a.z * b.y; acc[2][2] += a.z * b.z; acc[2][3] += a.z * b.w;
            acc[3][0] += a.w * b.x; acc[3][1] += a.w * b.y; acc[3][2] += a.w * b.z; acc[3][3] += a.w * b.w;
        }
        __syncthreads();
    }
    float4 bb = *(const float4*)&bproj[bcol + tc * 4];
    #pragma unroll
    for (int i = 0; i < 4; ++i) {
        int r = brow + tr * 4 + i;
        float4 o = {acc[i][0] + bb.x, acc[i][1] + bb.y, acc[i][2] + bb.z, acc[i][3] + bb.w};
        *(float4*)&z[(size_t)r * TOTAL_DIM + bcol + tc * 4] = o;
    }
}

__global__ __launch_bounds__(256)
void code_score(const float* __restrict__ z, int* __restrict__ code,
                float* __restrict__ score, int NT)
{
    int idx = blockIdx.x * 256 + threadIdx.x;
    if (idx >= NT) return;
    int n = idx >> 6, t = idx & 63;
    const float* zp = z + (size_t)n * TOTAL_DIM + t * CODE_LEN;
    float s = 1.0f; int c = 0;
    #pragma unroll
    for (int i = 0; i < CODE_LEN; ++i) {
        float v = zp[i];
        s *= 0.5f * (1.0f + tanhf(fabsf(v)));
        c |= (v > 0.0f) ? (1 << i) : 0;
    }
    code[idx] = c; score[idx] = s;
}

__global__ __launch_bounds__(256)
void gather_sum_f32(const float* __restrict__ tables, const float* __restrict__ bias,
                    const int* __restrict__ code, const float* __restrict__ score,
                    float* __restrict__ out)
{
    __shared__ int   sc[NUM_TABLE];
    __shared__ float sw[NUM_TABLE];
    const int n = blockIdx.x, tid = threadIdx.x;
    if (tid < NUM_TABLE) {
        sc[tid] = code[n * NUM_TABLE + tid];
        sw[tid] = score[n * NUM_TABLE + tid];
    }
    __syncthreads();
    float4 acc = *(const float4*)&bias[tid * 4];
    #pragma unroll 4
    for (int t = 0; t < NUM_TABLE; ++t) {
        const float* row = tables + ((size_t)(t * TABLE_SZ + sc[t])) * OUTD;
        float4 v = *(const float4*)&row[tid * 4];
        float w = sw[t];
        acc.x += v.x * w; acc.y += v.y * w; acc.z += v.z * w; acc.w += v.w * w;
    }
    *(float4*)&out[(size_t)n * OUTD + tid * 4] = acc;
}

extern "C" void kernel_launch(void* const* d_in, const int* in_sizes, int n_in,
                              void* d_out, int out_size, void* d_ws, size_t ws_size,
                              hipStream_t stream) {
    const float* x      = (const float*)d_in[0];
    const float* W      = (const float*)d_in[1];
    const float* bproj  = (const float*)d_in[2];
    const float* tables = (const float*)d_in[3];
    const float* bias   = (const float*)d_in[4];
    float* out = (float*)d_out;

    const int N = in_sizes[0] / HIDDEN;           // 8192

    // ws: z | code | score | wf | flags | cnt | btab
    char* ws = (char*)d_ws;
    size_t off_z     = 0;
    size_t off_code  = off_z     + (size_t)N * TOTAL_DIM * sizeof(float);
    size_t off_score = off_code  + (size_t)N * NUM_TABLE * sizeof(int);
    size_t off_wf    = off_score + (size_t)N * NUM_TABLE * sizeof(float);
    size_t off_flags = off_wf    + (size_t)TOTAL_DIM * HIDDEN * sizeof(_Float16);
    size_t off_cnt   = off_flags + (size_t)FCAP * sizeof(uint32_t);
    size_t off_btab  = (off_cnt + 4 + 255) & ~(size_t)255;
    size_t tab_elems = (size_t)NUM_TABLE * TABLE_SZ * OUTD;
    size_t need      = off_btab + tab_elems * sizeof(ushort);

    float*    z     = (float*)(ws + off_z);
    int*      code  = (int*)(ws + off_code);
    float*    score = (float*)(ws + off_score);
    _Float16* wf    = (_Float16*)(ws + off_wf);
    uint32_t* flags = (uint32_t*)(ws + off_flags);
    uint32_t* cnt   = (uint32_t*)(ws + off_cnt);
    ushort*   btab  = (ushort*)(ws + off_btab);

    int NT = N * NUM_TABLE;

    if (ws_size >= need) {
        dim3 gw(TOTAL_DIM / 32, HIDDEN / 32);
        cvt_wt<<<gw, 256, 0, stream>>>(W, wf);
        (void)hipMemsetAsync(cnt, 0, 4, stream);

        gemm_f16<<<GEMM_MB * GEMM_NB, 256, 0, stream>>>(x, wf, bproj, z);

        code_score2<<<(NT + 255) / 256, 256, 0, stream>>>(z, code, score, flags, cnt, NT);
        fixz<<<512, 256, 0, stream>>>(x, W, bproj, code, flags, cnt);

        convert_tables<<<2048, 256, 0, stream>>>(tables, btab, (int)(tab_elems / 4));
        gather_sum_bf16<<<N, 256, 0, stream>>>(btab, bias, code, score, out);
    } else {
        dim3 g1(N / BM, TOTAL_DIM / BN);
        gemm_proj<<<g1, 256, 0, stream>>>(x, W, bproj, z);
        code_score<<<(NT + 255) / 256, 256, 0, stream>>>(z, code, score, NT);
        gather_sum_f32<<<N, 256, 0, stream>>>(tables, bias, code, score, out);
    }
}

// Round 12
// 405.960 us; speedup vs baseline: 1.1476x; 1.1301x over previous
//
#include <hip/hip_runtime.h>
#include <cstddef>
#include <cstdint>

#define HIDDEN    1024
#define OUTD      1024
#define NUM_TABLE 64
#define CODE_LEN  10
#define TABLE_SZ  1024
#define TOTAL_DIM 640

#define TAU   3e-3f
#define FCAP  131072u

typedef float    fx4   __attribute__((ext_vector_type(4)));
typedef ushort   ux4   __attribute__((ext_vector_type(4)));
typedef _Float16 f16x4 __attribute__((ext_vector_type(4)));
typedef _Float16 f16x8 __attribute__((ext_vector_type(8)));
typedef float    f32x4 __attribute__((ext_vector_type(4)));

static __device__ __forceinline__ ushort f2bf(float f) {   // RNE, for tables
    uint32_t u = __float_as_uint(f);
    return (ushort)((u + 0x7FFFu + ((u >> 16) & 1u)) >> 16);
}

// ------ convert + transpose W: [1024][640] f32 -> wf fp16 + wt32 fp32, [640][1024] --
__global__ __launch_bounds__(256)
void cvt_wt(const float* __restrict__ W, _Float16* __restrict__ wf,
            float* __restrict__ wt32)
{
    __shared__ float t[32][33];
    const int d0 = blockIdx.x * 32, k0 = blockIdx.y * 32;
    const int lx = threadIdx.x & 31, ly = threadIdx.x >> 5;   // 32 x 8
    #pragma unroll
    for (int i = 0; i < 32; i += 8)
        t[ly + i][lx] = W[(size_t)(k0 + ly + i) * TOTAL_DIM + d0 + lx];
    __syncthreads();
    #pragma unroll
    for (int i = 0; i < 32; i += 8) {
        float v = t[lx][ly + i];              // = W[k0+lx][d0+ly+i]
        size_t o = (size_t)(d0 + ly + i) * HIDDEN + k0 + lx;
        wf[o]   = (_Float16)v;
        wt32[o] = v;
    }
}

// ---------------- fp16 MFMA GEMM: z = x @ W + b (round-6 structure) ------------
// x [N,1024] fp32 (converted to fp16 in-register during staging),
// wf [640][1024] fp16. 128x128 tile, BK=32, 4 waves (2x2), 4x4 frags 16x16x32.
#define GBM 128
#define GBN 128
#define GBK 32
#define LDK 40   // padded inner dim (80 B row stride, 16B-aligned)
#define GEMM_MB (8192 / GBM)              // 64
#define GEMM_NB (TOTAL_DIM / GBN)         // 5

__global__ __launch_bounds__(256)
void gemm_f16(const float* __restrict__ x, const _Float16* __restrict__ wf,
              const float* __restrict__ bproj, float* __restrict__ z)
{
    __shared__ _Float16 As[GBM][LDK];
    __shared__ _Float16 Bs[GBN][LDK];

    const int tid  = threadIdx.x;
    const int lane = tid & 63, wid = tid >> 6;
    const int wr = wid >> 1, wc = wid & 1;            // 2x2 wave grid
    const int brow = blockIdx.x * GBM;
    const int bcol = blockIdx.y * GBN;
    const int fr = lane & 15, fq = lane >> 4;

    f32x4 acc[4][4] = {};

    for (int k0 = 0; k0 < HIDDEN; k0 += GBK) {
        // stage A: 128x32 fp32 -> fp16 in-register -> LDS
        #pragma unroll
        for (int i = 0; i < 4; ++i) {
            int c = tid + i * 256;                    // 0..1023
            int r = c >> 3, kc = (c & 7) * 4;
            fx4 v = *(const fx4*)&x[(size_t)(brow + r) * HIDDEN + k0 + kc];
            f16x4 h;
            h[0] = (_Float16)v.x; h[1] = (_Float16)v.y;
            h[2] = (_Float16)v.z; h[3] = (_Float16)v.w;
            *(f16x4*)&As[r][kc] = h;
        }
        // stage B^T: 128n x 32k fp16, 16B per thread
        #pragma unroll
        for (int i = 0; i < 2; ++i) {
            int c = tid + i * 256;                    // 0..511
            int nr = c >> 2, kc = (c & 3) * 8;
            *(f16x8*)&Bs[nr][kc] =
                *(const f16x8*)&wf[(size_t)(bcol + nr) * HIDDEN + k0 + kc];
        }
        __syncthreads();

        f16x8 a[4], b[4];
        #pragma unroll
        for (int m = 0; m < 4; ++m)
            a[m] = *(const f16x8*)&As[wr * 64 + m * 16 + fr][fq * 8];
        #pragma unroll
        for (int n = 0; n < 4; ++n)
            b[n] = *(const f16x8*)&Bs[wc * 64 + n * 16 + fr][fq * 8];
        #pragma unroll
        for (int m = 0; m < 4; ++m)
            #pragma unroll
            for (int n = 0; n < 4; ++n)
                acc[m][n] = __builtin_amdgcn_mfma_f32_16x16x32_f16(a[m], b[n], acc[m][n], 0, 0, 0);
        __syncthreads();
    }

    // epilogue: +bias; C/D mapping col=lane&15, row=(lane>>4)*4+reg
    #pragma unroll
    for (int n = 0; n < 4; ++n) {
        int col = bcol + wc * 64 + n * 16 + fr;
        float bb = bproj[col];
        #pragma unroll
        for (int m = 0; m < 4; ++m) {
            int rbase = brow + wr * 64 + m * 16 + fq * 4;
            #pragma unroll
            for (int j = 0; j < 4; ++j)
                z[(size_t)(rbase + j) * TOTAL_DIM + col] = acc[m][n][j] + bb;
        }
    }
}

// ------- code / score + near-zero flagging (ballot-aggregated, sign in bit31) ----
__global__ __launch_bounds__(256)
void code_score2(const float* __restrict__ z, int* __restrict__ code,
                 float* __restrict__ score, uint32_t* __restrict__ flags,
                 uint32_t* __restrict__ cnt, int NT)
{
    int idx = blockIdx.x * 256 + threadIdx.x;
    bool live = idx < NT;
    int n = idx >> 6;
    int t = idx & 63;
    const int lane = threadIdx.x & 63;
    const float* zp = z + (size_t)n * TOTAL_DIM + t * CODE_LEN;
    float s = 1.0f;
    int   c = 0;
    #pragma unroll
    for (int i = 0; i < CODE_LEN; ++i) {
        float v = live ? zp[i] : 1.0f;
        bool  p = fabsf(v) < TAU;                   // sign uncertain under fp16
        unsigned long long mask = __ballot(p);
        if (mask) {                                 // one atomic per wave per i
            int nact = __popcll(mask);
            int lead = __ffsll((long long)mask) - 1;
            uint32_t base = 0;
            if (lane == lead) base = atomicAdd(cnt, (uint32_t)nact);
            base = (uint32_t)__shfl((int)base, lead);
            if (p) {
                uint32_t slot = base + (uint32_t)__popcll(mask & ((1ull << lane) - 1ull));
                if (slot < FCAP) {
                    uint32_t nd = (uint32_t)(n * TOTAL_DIM + t * CODE_LEN + i);
                    flags[slot] = nd | (v > 0.0f ? 0x80000000u : 0u);
                }
            }
        }
        s *= 0.5f * (1.0f + tanhf(fabsf(v)));
        c |= (v > 0.0f) ? (1 << i) : 0;
    }
    if (live) {
        code[idx]  = c;
        score[idx] = s;
    }
}

// ----- exact fp32 recompute of flagged z via transposed W (coalesced); fix bits ----
__global__ __launch_bounds__(256)
void fixz(const float* __restrict__ x, const float* __restrict__ wt32,
          const float* __restrict__ bproj, int* __restrict__ code,
          const uint32_t* __restrict__ flags, const uint32_t* __restrict__ cnt)
{
    const int lane = threadIdx.x & 63;
    const int gw   = (blockIdx.x * 256 + threadIdx.x) >> 6;
    const int nw   = (gridDim.x * 256) >> 6;
    uint32_t count = *cnt;
    if (count > FCAP) count = FCAP;

    for (uint32_t f = gw; f < count; f += nw) {
        uint32_t fl = flags[f];
        uint32_t e  = fl & 0x7FFFFFFFu;
        int oldpos  = (int)(fl >> 31);
        int n = e / TOTAL_DIM, d = e % TOTAL_DIM;
        const float* xr = x    + (size_t)n * HIDDEN;
        const float* wr = wt32 + (size_t)d * HIDDEN;
        float p = 0.0f;
        #pragma unroll
        for (int j = 0; j < 16; ++j) {
            int k = lane + j * 64;
            p = fmaf(xr[k], wr[k], p);
        }
        #pragma unroll
        for (int off = 32; off; off >>= 1) p += __shfl_xor(p, off);
        float v = p + bproj[d];
        if (lane == 0) {
            if ((v > 0.0f) != (oldpos != 0)) {
                int t = d / CODE_LEN, i = d % CODE_LEN;
                atomicXor(&code[n * NUM_TABLE + t], 1 << i);
            }
        }
    }
}

// ---------------- fp32 -> bf16 table conversion (RNE), nt loads ----------------
__global__ __launch_bounds__(256)
void convert_tables(const float* __restrict__ t, ushort* __restrict__ o, int n4)
{
    const fx4* tp = (const fx4*)t;
    int stride = gridDim.x * 256;
    for (int i = blockIdx.x * 256 + threadIdx.x; i < n4; i += stride) {
        fx4 v = __builtin_nontemporal_load(&tp[i]);
        ux4 u;
        u.x = f2bf(v.x); u.y = f2bf(v.y); u.z = f2bf(v.z); u.w = f2bf(v.w);
        *(ux4*)&o[(size_t)i * 4] = u;
    }
}

// ---------------- gather + weighted sum (bf16 tables, full 1024-col rows) --------
__global__ __launch_bounds__(256)
void gather_sum_bf16(const ushort* __restrict__ btab, const float* __restrict__ bias,
                     const int* __restrict__ code, const float* __restrict__ score,
                     float* __restrict__ out)
{
    __shared__ int   sc[NUM_TABLE];
    __shared__ float sw[NUM_TABLE];

    const int n   = blockIdx.x;
    const int tid = threadIdx.x;

    if (tid < NUM_TABLE) {
        sc[tid] = code[n * NUM_TABLE + tid];
        sw[tid] = score[n * NUM_TABLE + tid];
    }
    __syncthreads();

    float4 acc = *(const float4*)&bias[tid * 4];

    #pragma unroll 4
    for (int t = 0; t < NUM_TABLE; ++t) {
        const ux4 v = *(const ux4*)&btab[((size_t)(t * TABLE_SZ + sc[t])) * OUTD + tid * 4];
        float w = sw[t];
        acc.x += w * __uint_as_float((uint32_t)v.x << 16);
        acc.y += w * __uint_as_float((uint32_t)v.y << 16);
        acc.z += w * __uint_as_float((uint32_t)v.z << 16);
        acc.w += w * __uint_as_float((uint32_t)v.w << 16);
    }

    *(float4*)&out[(size_t)n * OUTD + tid * 4] = acc;
}

// ---------------- fallback path (ws too small): fp32 vector GEMM + f32 gather ----
#define BM 64
#define BN 64
#define BK 32
__global__ __launch_bounds__(256)
void gemm_proj(const float* __restrict__ x, const float* __restrict__ W,
               const float* __restrict__ bproj, float* __restrict__ z)
{
    __shared__ float As[BK][BM + 4];
    __shared__ float Bs[BK][BN];
    const int tid  = threadIdx.x;
    const int brow = blockIdx.x * BM;
    const int bcol = blockIdx.y * BN;
    const int tr   = tid >> 4;
    const int tc   = tid & 15;
    float acc[4][4] = {};
    for (int k0 = 0; k0 < HIDDEN; k0 += BK) {
        #pragma unroll
        for (int i = 0; i < 2; ++i) {
            int lin = tid + i * 256;
            int r = lin >> 3, c8 = lin & 7;
            float4 a = *(const float4*)&x[(size_t)(brow + r) * HIDDEN + k0 + c8 * 4];
            As[c8 * 4 + 0][r] = a.x; As[c8 * 4 + 1][r] = a.y;
            As[c8 * 4 + 2][r] = a.z; As[c8 * 4 + 3][r] = a.w;
        }
        #pragma unroll
        for (int i = 0; i < 2; ++i) {
            int lin = tid + i * 256;
            int kk = lin >> 4, m4 = lin & 15;
            *(float4*)&Bs[kk][m4 * 4] =
                *(const float4*)&W[(size_t)(k0 + kk) * TOTAL_DIM + bcol + m4 * 4];
        }
        __syncthreads();
        #pragma unroll
        for (int kk = 0; kk < BK; ++kk) {
            float4 a = *(const float4*)&As[kk][tr * 4];
            float4 b = *(const float4*)&Bs[kk][tc * 4];
            acc[0][0] += a.x * b.x; acc[0][1] += a.x * b.y; acc[0][2] += a.x * b.z; acc[0][3] += a.x * b.w;
            acc[1][0] += a.y * b.x; acc[1][1] += a.y * b.y; acc[1][2] += a.y * b.z; acc[1][3] += a.y * b.w;
            acc[2][0] += a.z * b.x; acc[2][1] += a.z * b.y; acc[2][2] += a.z * b.z; acc[2][3] += a.z * b.w;
            acc[3][0] += a.w * b.x; acc[3][1] += a.w * b.y; acc[3][2] += a.w * b.z; acc[3][3] += a.w * b.w;
        }
        __syncthreads();
    }
    float4 bb = *(const float4*)&bproj[bcol + tc * 4];
    #pragma unroll
    for (int i = 0; i < 4; ++i) {
        int r = brow + tr * 4 + i;
        float4 o = {acc[i][0] + bb.x, acc[i][1] + bb.y, acc[i][2] + bb.z, acc[i][3] + bb.w};
        *(float4*)&z[(size_t)r * TOTAL_DIM + bcol + tc * 4] = o;
    }
}

__global__ __launch_bounds__(256)
void code_score(const float* __restrict__ z, int* __restrict__ code,
                float* __restrict__ score, int NT)
{
    int idx = blockIdx.x * 256 + threadIdx.x;
    if (idx >= NT) return;
    int n = idx >> 6, t = idx & 63;
    const float* zp = z + (size_t)n * TOTAL_DIM + t * CODE_LEN;
    float s = 1.0f; int c = 0;
    #pragma unroll
    for (int i = 0; i < CODE_LEN; ++i) {
        float v = zp[i];
        s *= 0.5f * (1.0f + tanhf(fabsf(v)));
        c |= (v > 0.0f) ? (1 << i) : 0;
    }
    code[idx] = c; score[idx] = s;
}

__global__ __launch_bounds__(256)
void gather_sum_f32(const float* __restrict__ tables, const float* __restrict__ bias,
                    const int* __restrict__ code, const float* __restrict__ score,
                    float* __restrict__ out)
{
    __shared__ int   sc[NUM_TABLE];
    __shared__ float sw[NUM_TABLE];
    const int n = blockIdx.x, tid = threadIdx.x;
    if (tid < NUM_TABLE) {
        sc[tid] = code[n * NUM_TABLE + tid];
        sw[tid] = score[n * NUM_TABLE + tid];
    }
    __syncthreads();
    float4 acc = *(const float4*)&bias[tid * 4];
    #pragma unroll 4
    for (int t = 0; t < NUM_TABLE; ++t) {
        const float* row = tables + ((size_t)(t * TABLE_SZ + sc[t])) * OUTD;
        float4 v = *(const float4*)&row[tid * 4];
        float w = sw[t];
        acc.x += v.x * w; acc.y += v.y * w; acc.z += v.z * w; acc.w += v.w * w;
    }
    *(float4*)&out[(size_t)n * OUTD + tid * 4] = acc;
}

extern "C" void kernel_launch(void* const* d_in, const int* in_sizes, int n_in,
                              void* d_out, int out_size, void* d_ws, size_t ws_size,
                              hipStream_t stream) {
    const float* x      = (const float*)d_in[0];
    const float* W      = (const float*)d_in[1];
    const float* bproj  = (const float*)d_in[2];
    const float* tables = (const float*)d_in[3];
    const float* bias   = (const float*)d_in[4];
    float* out = (float*)d_out;

    const int N = in_sizes[0] / HIDDEN;           // 8192

    // ws: z | code | score | wf | wt32 | flags | cnt | btab
    char* ws = (char*)d_ws;
    size_t off_z     = 0;
    size_t off_code  = off_z     + (size_t)N * TOTAL_DIM * sizeof(float);
    size_t off_score = off_code  + (size_t)N * NUM_TABLE * sizeof(int);
    size_t off_wf    = off_score + (size_t)N * NUM_TABLE * sizeof(float);
    size_t off_wt32  = off_wf    + (size_t)TOTAL_DIM * HIDDEN * sizeof(_Float16);
    size_t off_flags = off_wt32  + (size_t)TOTAL_DIM * HIDDEN * sizeof(float);
    size_t off_cnt   = off_flags + (size_t)FCAP * sizeof(uint32_t);
    size_t off_btab  = (off_cnt + 4 + 255) & ~(size_t)255;
    size_t tab_elems = (size_t)NUM_TABLE * TABLE_SZ * OUTD;
    size_t need      = off_btab + tab_elems * sizeof(ushort);

    float*    z     = (float*)(ws + off_z);
    int*      code  = (int*)(ws + off_code);
    float*    score = (float*)(ws + off_score);
    _Float16* wf    = (_Float16*)(ws + off_wf);
    float*    wt32  = (float*)(ws + off_wt32);
    uint32_t* flags = (uint32_t*)(ws + off_flags);
    uint32_t* cnt   = (uint32_t*)(ws + off_cnt);
    ushort*   btab  = (ushort*)(ws + off_btab);

    int NT = N * NUM_TABLE;

    if (ws_size >= need) {
        dim3 gw(TOTAL_DIM / 32, HIDDEN / 32);
        cvt_wt<<<gw, 256, 0, stream>>>(W, wf, wt32);
        (void)hipMemsetAsync(cnt, 0, 4, stream);

        dim3 g1(N / GBM, TOTAL_DIM / GBN);
        gemm_f16<<<g1, 256, 0, stream>>>(x, wf, bproj, z);

        code_score2<<<(NT + 255) / 256, 256, 0, stream>>>(z, code, score, flags, cnt, NT);
        fixz<<<512, 256, 0, stream>>>(x, wt32, bproj, code, flags, cnt);

        convert_tables<<<2048, 256, 0, stream>>>(tables, btab, (int)(tab_elems / 4));
        gather_sum_bf16<<<N, 256, 0, stream>>>(btab, bias, code, score, out);
    } else {
        dim3 g1(N / BM, TOTAL_DIM / BN);
        gemm_proj<<<g1, 256, 0, stream>>>(x, W, bproj, z);
        code_score<<<(NT + 255) / 256, 256, 0, stream>>>(z, code, score, NT);
        gather_sum_f32<<<N, 256, 0, stream>>>(tables, bias, code, score, out);
    }
}

// Round 13
// 327.181 us; speedup vs baseline: 1.4239x; 1.2408x over previous
//
#include <hip/hip_runtime.h>
#include <cstddef>
#include <cstdint>

#define HIDDEN    1024
#define OUTD      1024
#define NUM_TABLE 64
#define CODE_LEN  10
#define TABLE_SZ  1024
#define TOTAL_DIM 640

#define TAU   1e-3f
#define FCAP  131072u

typedef float  fx4    __attribute__((ext_vector_type(4)));
typedef ushort ux4    __attribute__((ext_vector_type(4)));
typedef ushort ux8    __attribute__((ext_vector_type(8)));
typedef short  bf16x8 __attribute__((ext_vector_type(8)));
typedef float  f32x4  __attribute__((ext_vector_type(4)));

// ---------- bf16 helpers (truncation split: v = hi + lo + O(2^-16 v)) ----------
struct bfp { ushort hi, lo; };
static __device__ __forceinline__ bfp split2(float v) {
    uint32_t u  = __float_as_uint(v);
    float    fh = __uint_as_float(u & 0xFFFF0000u);
    uint32_t ul = __float_as_uint(v - fh);   // exact subtraction
    bfp r; r.hi = (ushort)(u >> 16); r.lo = (ushort)(ul >> 16);
    return r;
}
static __device__ __forceinline__ ushort f2bf(float f) {   // RNE, for tables
    uint32_t u = __float_as_uint(f);
    return (ushort)((u + 0x7FFFu + ((u >> 16) & 1u)) >> 16);
}

// ---- split + transpose W: [1024][640] f32 -> wht/wlt bf16 + wt32 f32, [640][1024] ----
__global__ __launch_bounds__(256)
void split_wt(const float* __restrict__ W, ushort* __restrict__ wht,
              ushort* __restrict__ wlt, float* __restrict__ wt32)
{
    __shared__ float t[32][33];
    const int d0 = blockIdx.x * 32, k0 = blockIdx.y * 32;
    const int lx = threadIdx.x & 31, ly = threadIdx.x >> 5;   // 32 x 8
    #pragma unroll
    for (int i = 0; i < 32; i += 8)
        t[ly + i][lx] = W[(size_t)(k0 + ly + i) * TOTAL_DIM + d0 + lx];
    __syncthreads();
    #pragma unroll
    for (int i = 0; i < 32; i += 8) {
        float v = t[lx][ly + i];              // = W[k0+lx][d0+ly+i]
        bfp s = split2(v);
        size_t o = (size_t)(d0 + ly + i) * HIDDEN + k0 + lx;
        wht[o] = s.hi; wlt[o] = s.lo; wt32[o] = v;
    }
}

// ---------------- fused: bf16x3 MFMA GEMM (64x64 tiles) + table convert ----------
// GEMM blocks 0..1279: z = x @ W + b; 64x64 tile, BK=32, 4 waves (2x2), 2x2 frags.
// Convert blocks 1280..2303: fp32 tables -> bf16 btab, grid-stride, nt loads.
#define GBM 64
#define GBN 64
#define GBK 32
#define LDK 40        // padded inner dim (80 B row stride)
#define GEMM_MB (8192 / GBM)                    // 128
#define GEMM_NB (TOTAL_DIM / GBN)               // 10
#define GEMM_BLKS (GEMM_MB * GEMM_NB)           // 1280
#define CONV_BLKS 1024

__global__ __launch_bounds__(256)
void gemm_convert(const float* __restrict__ x, const ushort* __restrict__ wht,
                  const ushort* __restrict__ wlt, const float* __restrict__ bproj,
                  float* __restrict__ z,
                  const float* __restrict__ tables, ushort* __restrict__ btab)
{
    __shared__ ushort Ah[GBM][LDK];
    __shared__ ushort Al[GBM][LDK];
    __shared__ ushort Bh[GBN][LDK];
    __shared__ ushort Bl[GBN][LDK];

    const int gb  = blockIdx.x;
    const int tid = threadIdx.x;

    if (gb >= GEMM_BLKS) {
        // ---- convert path: grid-stride over 16.78M float4s, nt loads ----
        const int cb = gb - GEMM_BLKS;                 // 0..1023
        const int n4 = NUM_TABLE * TABLE_SZ * (OUTD / 4);
        const fx4* tp = (const fx4*)tables;
        const int stride = CONV_BLKS * 256;
        for (int i = cb * 256 + tid; i < n4; i += stride) {
            fx4 v = __builtin_nontemporal_load(&tp[i]);
            ux4 u;
            u.x = f2bf(v.x); u.y = f2bf(v.y); u.z = f2bf(v.z); u.w = f2bf(v.w);
            *(ux4*)&btab[(size_t)i * 4] = u;
        }
        return;
    }

    // ---- GEMM path ----
    const int lane = tid & 63, wid = tid >> 6;
    const int wr = wid >> 1, wc = wid & 1;             // 2x2 wave grid (32x32 each)
    const int brow = (gb % GEMM_MB) * GBM;
    const int bcol = (gb / GEMM_MB) * GBN;
    const int fr = lane & 15, fq = lane >> 4;

    f32x4 acc[2][2] = {};

    for (int k0 = 0; k0 < HIDDEN; k0 += GBK) {
        // stage A: 64x32 fp32, split in-register -> Ah/Al (2 fx4 per thread)
        #pragma unroll
        for (int i = 0; i < 2; ++i) {
            int c = tid + i * 256;                     // 0..511
            int r = c >> 3, kc = (c & 7) * 4;
            fx4 v = *(const fx4*)&x[(size_t)(brow + r) * HIDDEN + k0 + kc];
            bfp s0 = split2(v.x), s1 = split2(v.y), s2 = split2(v.z), s3 = split2(v.w);
            ux4 h, l;
            h.x = s0.hi; l.x = s0.lo;
            h.y = s1.hi; l.y = s1.lo;
            h.z = s2.hi; l.z = s2.lo;
            h.w = s3.hi; l.w = s3.lo;
            *(ux4*)&Ah[r][kc] = h;
            *(ux4*)&Al[r][kc] = l;
        }
        // stage B^T: 64n x 32k bf16 each, one ux8 per thread per table
        {
            int nr = tid >> 2, kc = (tid & 3) * 8;
            size_t o = (size_t)(bcol + nr) * HIDDEN + k0 + kc;
            *(ux8*)&Bh[nr][kc] = *(const ux8*)&wht[o];
            *(ux8*)&Bl[nr][kc] = *(const ux8*)&wlt[o];
        }
        __syncthreads();

        bf16x8 ah[2], al[2], bh[2], bl[2];
        #pragma unroll
        for (int m = 0; m < 2; ++m) {
            ah[m] = *(const bf16x8*)&Ah[wr * 32 + m * 16 + fr][fq * 8];
            al[m] = *(const bf16x8*)&Al[wr * 32 + m * 16 + fr][fq * 8];
        }
        #pragma unroll
        for (int n = 0; n < 2; ++n) {
            bh[n] = *(const bf16x8*)&Bh[wc * 32 + n * 16 + fr][fq * 8];
            bl[n] = *(const bf16x8*)&Bl[wc * 32 + n * 16 + fr][fq * 8];
        }
        #pragma unroll
        for (int m = 0; m < 2; ++m)
            #pragma unroll
            for (int n = 0; n < 2; ++n) {
                acc[m][n] = __builtin_amdgcn_mfma_f32_16x16x32_bf16(ah[m], bh[n], acc[m][n], 0, 0, 0);
                acc[m][n] = __builtin_amdgcn_mfma_f32_16x16x32_bf16(ah[m], bl[n], acc[m][n], 0, 0, 0);
                acc[m][n] = __builtin_amdgcn_mfma_f32_16x16x32_bf16(al[m], bh[n], acc[m][n], 0, 0, 0);
            }
        __syncthreads();
    }

    // epilogue: +bias; C/D mapping col=lane&15, row=(lane>>4)*4+reg  [m89]
    #pragma unroll
    for (int n = 0; n < 2; ++n) {
        int col = bcol + wc * 32 + n * 16 + fr;
        float bb = bproj[col];
        #pragma unroll
        for (int m = 0; m < 2; ++m) {
            int rbase = brow + wr * 32 + m * 16 + fq * 4;
            #pragma unroll
            for (int j = 0; j < 4; ++j)
                z[(size_t)(rbase + j) * TOTAL_DIM + col] = acc[m][n][j] + bb;
        }
    }
}

// ------- code / score + near-zero flagging (ballot-aggregated, sign in bit31) ----
__global__ __launch_bounds__(256)
void code_score2(const float* __restrict__ z, int* __restrict__ code,
                 float* __restrict__ score, uint32_t* __restrict__ flags,
                 uint32_t* __restrict__ cnt, int NT)
{
    int idx = blockIdx.x * 256 + threadIdx.x;
    bool live = idx < NT;
    int n = idx >> 6;
    int t = idx & 63;
    const int lane = threadIdx.x & 63;
    const float* zp = z + (size_t)n * TOTAL_DIM + t * CODE_LEN;
    float s = 1.0f;
    int   c = 0;
    #pragma unroll
    for (int i = 0; i < CODE_LEN; ++i) {
        float v = live ? zp[i] : 1.0f;
        bool  p = fabsf(v) < TAU;                   // sign uncertain under bf16x3
        unsigned long long mask = __ballot(p);
        if (mask) {                                 // one atomic per wave per i
            int nact = __popcll(mask);
            int lead = __ffsll((long long)mask) - 1;
            uint32_t base = 0;
            if (lane == lead) base = atomicAdd(cnt, (uint32_t)nact);
            base = (uint32_t)__shfl((int)base, lead);
            if (p) {
                uint32_t slot = base + (uint32_t)__popcll(mask & ((1ull << lane) - 1ull));
                if (slot < FCAP) {
                    uint32_t nd = (uint32_t)(n * TOTAL_DIM + t * CODE_LEN + i);
                    flags[slot] = nd | (v > 0.0f ? 0x80000000u : 0u);
                }
            }
        }
        s *= 0.5f * (1.0f + tanhf(fabsf(v)));
        c |= (v > 0.0f) ? (1 << i) : 0;
    }
    if (live) {
        code[idx]  = c;
        score[idx] = s;
    }
}

// ----- exact fp32 recompute of flagged z via transposed W (coalesced); fix bits ----
__global__ __launch_bounds__(256)
void fixz(const float* __restrict__ x, const float* __restrict__ wt32,
          const float* __restrict__ bproj, int* __restrict__ code,
          const uint32_t* __restrict__ flags, const uint32_t* __restrict__ cnt)
{
    const int lane = threadIdx.x & 63;
    const int gw   = (blockIdx.x * 256 + threadIdx.x) >> 6;
    const int nw   = (gridDim.x * 256) >> 6;
    uint32_t count = *cnt;
    if (count > FCAP) count = FCAP;

    for (uint32_t f = gw; f < count; f += nw) {
        uint32_t fl = flags[f];
        uint32_t e  = fl & 0x7FFFFFFFu;
        int oldpos  = (int)(fl >> 31);
        int n = e / TOTAL_DIM, d = e % TOTAL_DIM;
        const float* xr = x    + (size_t)n * HIDDEN;
        const float* wr = wt32 + (size_t)d * HIDDEN;
        float p = 0.0f;
        #pragma unroll
        for (int j = 0; j < 16; ++j) {
            int k = lane + j * 64;
            p = fmaf(xr[k], wr[k], p);
        }
        #pragma unroll
        for (int off = 32; off; off >>= 1) p += __shfl_xor(p, off);
        float v = p + bproj[d];
        if (lane == 0) {
            if ((v > 0.0f) != (oldpos != 0)) {
                int t = d / CODE_LEN, i = d % CODE_LEN;
                atomicXor(&code[n * NUM_TABLE + t], 1 << i);
            }
        }
    }
}

// ---------------- gather + weighted sum (bf16 tables, full 1024-col rows) --------
__global__ __launch_bounds__(256)
void gather_sum_bf16(const ushort* __restrict__ btab, const float* __restrict__ bias,
                     const int* __restrict__ code, const float* __restrict__ score,
                     float* __restrict__ out)
{
    __shared__ int   sc[NUM_TABLE];
    __shared__ float sw[NUM_TABLE];

    const int n   = blockIdx.x;
    const int tid = threadIdx.x;

    if (tid < NUM_TABLE) {
        sc[tid] = code[n * NUM_TABLE + tid];
        sw[tid] = score[n * NUM_TABLE + tid];
    }
    __syncthreads();

    float4 acc = *(const float4*)&bias[tid * 4];

    #pragma unroll 4
    for (int t = 0; t < NUM_TABLE; ++t) {
        const ux4 v = *(const ux4*)&btab[((size_t)(t * TABLE_SZ + sc[t])) * OUTD + tid * 4];
        float w = sw[t];
        acc.x += w * __uint_as_float((uint32_t)v.x << 16);
        acc.y += w * __uint_as_float((uint32_t)v.y << 16);
        acc.z += w * __uint_as_float((uint32_t)v.z << 16);
        acc.w += w * __uint_as_float((uint32_t)v.w << 16);
    }

    *(float4*)&out[(size_t)n * OUTD + tid * 4] = acc;
}

// ---------------- fallback path (ws too small): fp32 vector GEMM + f32 gather ----
#define BM 64
#define BN 64
#define BK 32
__global__ __launch_bounds__(256)
void gemm_proj(const float* __restrict__ x, const float* __restrict__ W,
               const float* __restrict__ bproj, float* __restrict__ z)
{
    __shared__ float As[BK][BM + 4];
    __shared__ float Bs[BK][BN];
    const int tid  = threadIdx.x;
    const int brow = blockIdx.x * BM;
    const int bcol = blockIdx.y * BN;
    const int tr   = tid >> 4;
    const int tc   = tid & 15;
    float acc[4][4] = {};
    for (int k0 = 0; k0 < HIDDEN; k0 += BK) {
        #pragma unroll
        for (int i = 0; i < 2; ++i) {
            int lin = tid + i * 256;
            int r = lin >> 3, c8 = lin & 7;
            float4 a = *(const float4*)&x[(size_t)(brow + r) * HIDDEN + k0 + c8 * 4];
            As[c8 * 4 + 0][r] = a.x; As[c8 * 4 + 1][r] = a.y;
            As[c8 * 4 + 2][r] = a.z; As[c8 * 4 + 3][r] = a.w;
        }
        #pragma unroll
        for (int i = 0; i < 2; ++i) {
            int lin = tid + i * 256;
            int kk = lin >> 4, m4 = lin & 15;
            *(float4*)&Bs[kk][m4 * 4] =
                *(const float4*)&W[(size_t)(k0 + kk) * TOTAL_DIM + bcol + m4 * 4];
        }
        __syncthreads();
        #pragma unroll
        for (int kk = 0; kk < BK; ++kk) {
            float4 a = *(const float4*)&As[kk][tr * 4];
            float4 b = *(const float4*)&Bs[kk][tc * 4];
            acc[0][0] += a.x * b.x; acc[0][1] += a.x * b.y; acc[0][2] += a.x * b.z; acc[0][3] += a.x * b.w;
            acc[1][0] += a.y * b.x; acc[1][1] += a.y * b.y; acc[1][2] += a.y * b.z; acc[1][3] += a.y * b.w;
            acc[2][0] += a.z * b.x; acc[2][1] += a.z * b.y; acc[2][2] += a.z * b.z; acc[2][3] += a.z * b.w;
            acc[3][0] += a.w * b.x; acc[3][1] += a.w * b.y; acc[3][2] += a.w * b.z; acc[3][3] += a.w * b.w;
        }
        __syncthreads();
    }
    float4 bb = *(const float4*)&bproj[bcol + tc * 4];
    #pragma unroll
    for (int i = 0; i < 4; ++i) {
        int r = brow + tr * 4 + i;
        float4 o = {acc[i][0] + bb.x, acc[i][1] + bb.y, acc[i][2] + bb.z, acc[i][3] + bb.w};
        *(float4*)&z[(size_t)r * TOTAL_DIM + bcol + tc * 4] = o;
    }
}

__global__ __launch_bounds__(256)
void code_score(const float* __restrict__ z, int* __restrict__ code,
                float* __restrict__ score, int NT)
{
    int idx = blockIdx.x * 256 + threadIdx.x;
    if (idx >= NT) return;
    int n = idx >> 6, t = idx & 63;
    const float* zp = z + (size_t)n * TOTAL_DIM + t * CODE_LEN;
    float s = 1.0f; int c = 0;
    #pragma unroll
    for (int i = 0; i < CODE_LEN; ++i) {
        float v = zp[i];
        s *= 0.5f * (1.0f + tanhf(fabsf(v)));
        c |= (v > 0.0f) ? (1 << i) : 0;
    }
    code[idx] = c; score[idx] = s;
}

__global__ __launch_bounds__(256)
void gather_sum_f32(const float* __restrict__ tables, const float* __restrict__ bias,
                    const int* __restrict__ code, const float* __restrict__ score,
                    float* __restrict__ out)
{
    __shared__ int   sc[NUM_TABLE];
    __shared__ float sw[NUM_TABLE];
    const int n = blockIdx.x, tid = threadIdx.x;
    if (tid < NUM_TABLE) {
        sc[tid] = code[n * NUM_TABLE + tid];
        sw[tid] = score[n * NUM_TABLE + tid];
    }
    __syncthreads();
    float4 acc = *(const float4*)&bias[tid * 4];
    #pragma unroll 4
    for (int t = 0; t < NUM_TABLE; ++t) {
        const float* row = tables + ((size_t)(t * TABLE_SZ + sc[t])) * OUTD;
        float4 v = *(const float4*)&row[tid * 4];
        float w = sw[t];
        acc.x += v.x * w; acc.y += v.y * w; acc.z += v.z * w; acc.w += v.w * w;
    }
    *(float4*)&out[(size_t)n * OUTD + tid * 4] = acc;
}

extern "C" void kernel_launch(void* const* d_in, const int* in_sizes, int n_in,
                              void* d_out, int out_size, void* d_ws, size_t ws_size,
                              hipStream_t stream) {
    const float* x      = (const float*)d_in[0];
    const float* W      = (const float*)d_in[1];
    const float* bproj  = (const float*)d_in[2];
    const float* tables = (const float*)d_in[3];
    const float* bias   = (const float*)d_in[4];
    float* out = (float*)d_out;

    const int N = in_sizes[0] / HIDDEN;           // 8192

    // ws: z | code | score | wht | wlt | wt32 | flags | cnt | btab
    char* ws = (char*)d_ws;
    size_t off_z     = 0;
    size_t off_code  = off_z     + (size_t)N * TOTAL_DIM * sizeof(float);
    size_t off_score = off_code  + (size_t)N * NUM_TABLE * sizeof(int);
    size_t off_wht   = off_score + (size_t)N * NUM_TABLE * sizeof(float);
    size_t off_wlt   = off_wht   + (size_t)TOTAL_DIM * HIDDEN * sizeof(ushort);
    size_t off_wt32  = off_wlt   + (size_t)TOTAL_DIM * HIDDEN * sizeof(ushort);
    size_t off_flags = off_wt32  + (size_t)TOTAL_DIM * HIDDEN * sizeof(float);
    size_t off_cnt   = off_flags + (size_t)FCAP * sizeof(uint32_t);
    size_t off_btab  = (off_cnt + 4 + 255) & ~(size_t)255;
    size_t tab_elems = (size_t)NUM_TABLE * TABLE_SZ * OUTD;
    size_t need      = off_btab + tab_elems * sizeof(ushort);

    float*    z     = (float*)(ws + off_z);
    int*      code  = (int*)(ws + off_code);
    float*    score = (float*)(ws + off_score);
    ushort*   wht   = (ushort*)(ws + off_wht);
    ushort*   wlt   = (ushort*)(ws + off_wlt);
    float*    wt32  = (float*)(ws + off_wt32);
    uint32_t* flags = (uint32_t*)(ws + off_flags);
    uint32_t* cnt   = (uint32_t*)(ws + off_cnt);
    ushort*   btab  = (ushort*)(ws + off_btab);

    int NT = N * NUM_TABLE;

    if (ws_size >= need) {
        dim3 gw(TOTAL_DIM / 32, HIDDEN / 32);
        split_wt<<<gw, 256, 0, stream>>>(W, wht, wlt, wt32);
        (void)hipMemsetAsync(cnt, 0, 4, stream);

        gemm_convert<<<GEMM_BLKS + CONV_BLKS, 256, 0, stream>>>(
            x, wht, wlt, bproj, z, tables, btab);

        code_score2<<<(NT + 255) / 256, 256, 0, stream>>>(z, code, score, flags, cnt, NT);
        fixz<<<512, 256, 0, stream>>>(x, wt32, bproj, code, flags, cnt);

        gather_sum_bf16<<<N, 256, 0, stream>>>(btab, bias, code, score, out);
    } else {
        dim3 g1(N / BM, TOTAL_DIM / BN);
        gemm_proj<<<g1, 256, 0, stream>>>(x, W, bproj, z);
        code_score<<<(NT + 255) / 256, 256, 0, stream>>>(z, code, score, NT);
        gather_sum_f32<<<N, 256, 0, stream>>>(tables, bias, code, score, out);
    }
}

// Round 14
// 325.180 us; speedup vs baseline: 1.4327x; 1.0062x over previous
//
#include <hip/hip_runtime.h>
#include <cstddef>
#include <cstdint>

#define HIDDEN    1024
#define OUTD      1024
#define NUM_TABLE 64
#define CODE_LEN  10
#define TABLE_SZ  1024
#define TOTAL_DIM 640

#define TAU   1e-3f
#define FCAP  131072u

typedef float  fx4    __attribute__((ext_vector_type(4)));
typedef ushort ux4    __attribute__((ext_vector_type(4)));
typedef ushort ux8    __attribute__((ext_vector_type(8)));
typedef short  bf16x8 __attribute__((ext_vector_type(8)));
typedef float  f32x4  __attribute__((ext_vector_type(4)));

// ---------- bf16 helpers (truncation split: v = hi + lo + O(2^-16 v)) ----------
struct bfp { ushort hi, lo; };
static __device__ __forceinline__ bfp split2(float v) {
    uint32_t u  = __float_as_uint(v);
    float    fh = __uint_as_float(u & 0xFFFF0000u);
    uint32_t ul = __float_as_uint(v - fh);   // exact subtraction
    bfp r; r.hi = (ushort)(u >> 16); r.lo = (ushort)(ul >> 16);
    return r;
}
static __device__ __forceinline__ ushort f2bf(float f) {   // RNE, for tables
    uint32_t u = __float_as_uint(f);
    return (ushort)((u + 0x7FFFu + ((u >> 16) & 1u)) >> 16);
}

// ---- split + transpose W: [1024][640] f32 -> wht/wlt bf16 + wt32 f32, [640][1024] ----
__global__ __launch_bounds__(256)
void split_wt(const float* __restrict__ W, ushort* __restrict__ wht,
              ushort* __restrict__ wlt, float* __restrict__ wt32)
{
    __shared__ float t[32][33];
    const int d0 = blockIdx.x * 32, k0 = blockIdx.y * 32;
    const int lx = threadIdx.x & 31, ly = threadIdx.x >> 5;   // 32 x 8
    #pragma unroll
    for (int i = 0; i < 32; i += 8)
        t[ly + i][lx] = W[(size_t)(k0 + ly + i) * TOTAL_DIM + d0 + lx];
    __syncthreads();
    #pragma unroll
    for (int i = 0; i < 32; i += 8) {
        float v = t[lx][ly + i];              // = W[k0+lx][d0+ly+i]
        bfp s = split2(v);
        size_t o = (size_t)(d0 + ly + i) * HIDDEN + k0 + lx;
        wht[o] = s.hi; wlt[o] = s.lo; wt32[o] = v;
    }
}

// ---------------- fused: bf16x3 MFMA GEMM (64x64 tiles) + table convert ----------
// GEMM blocks 0..1279: z = x @ W + b; 64x64 tile, BK=32, 4 waves (2x2), 2x2 frags.
// Convert blocks 1280..2303: fp32 tables -> bf16 btab in column-grouped layout
//   btab[group][table][row][32 cols], group = col/32  (4 MB slice per group).
#define GBM 64
#define GBN 64
#define GBK 32
#define LDK 40        // padded inner dim (80 B row stride)
#define GEMM_MB (8192 / GBM)                    // 128
#define GEMM_NB (TOTAL_DIM / GBN)               // 10
#define GEMM_BLKS (GEMM_MB * GEMM_NB)           // 1280
#define CONV_BLKS 1024
#define CPG 32                                  // cols per group
#define NGRP (OUTD / CPG)                       // 32

__global__ __launch_bounds__(256)
void gemm_convert(const float* __restrict__ x, const ushort* __restrict__ wht,
                  const ushort* __restrict__ wlt, const float* __restrict__ bproj,
                  float* __restrict__ z,
                  const float* __restrict__ tables, ushort* __restrict__ btab)
{
    __shared__ ushort Ah[GBM][LDK];
    __shared__ ushort Al[GBM][LDK];
    __shared__ ushort Bh[GBN][LDK];
    __shared__ ushort Bl[GBN][LDK];

    const int gb  = blockIdx.x;
    const int tid = threadIdx.x;

    if (gb >= GEMM_BLKS) {
        // ---- convert path: grid-stride, nt loads, grouped-layout writes ----
        const int cb = gb - GEMM_BLKS;                 // 0..1023
        const int n4 = NUM_TABLE * TABLE_SZ * (OUTD / 4);
        const fx4* tp = (const fx4*)tables;
        const int stride = CONV_BLKS * 256;
        for (int i = cb * 256 + tid; i < n4; i += stride) {
            fx4 v = __builtin_nontemporal_load(&tp[i]);
            ux4 u;
            u.x = f2bf(v.x); u.y = f2bf(v.y); u.z = f2bf(v.z); u.w = f2bf(v.w);
            int col4 = (i & 255) * 4;                  // 0..1020
            int row  = (i >> 8) & 1023;
            int t    = i >> 18;                        // 0..63
            int g    = col4 >> 5;
            int c    = col4 & 31;
            size_t o = ((((size_t)g * NUM_TABLE + t) * TABLE_SZ + row) << 5) + c;
            *(ux4*)&btab[o] = u;
        }
        return;
    }

    // ---- GEMM path ----
    const int lane = tid & 63, wid = tid >> 6;
    const int wr = wid >> 1, wc = wid & 1;             // 2x2 wave grid (32x32 each)
    const int brow = (gb % GEMM_MB) * GBM;
    const int bcol = (gb / GEMM_MB) * GBN;
    const int fr = lane & 15, fq = lane >> 4;

    f32x4 acc[2][2] = {};

    for (int k0 = 0; k0 < HIDDEN; k0 += GBK) {
        #pragma unroll
        for (int i = 0; i < 2; ++i) {
            int c = tid + i * 256;                     // 0..511
            int r = c >> 3, kc = (c & 7) * 4;
            fx4 v = *(const fx4*)&x[(size_t)(brow + r) * HIDDEN + k0 + kc];
            bfp s0 = split2(v.x), s1 = split2(v.y), s2 = split2(v.z), s3 = split2(v.w);
            ux4 h, l;
            h.x = s0.hi; l.x = s0.lo;
            h.y = s1.hi; l.y = s1.lo;
            h.z = s2.hi; l.z = s2.lo;
            h.w = s3.hi; l.w = s3.lo;
            *(ux4*)&Ah[r][kc] = h;
            *(ux4*)&Al[r][kc] = l;
        }
        {
            int nr = tid >> 2, kc = (tid & 3) * 8;
            size_t o = (size_t)(bcol + nr) * HIDDEN + k0 + kc;
            *(ux8*)&Bh[nr][kc] = *(const ux8*)&wht[o];
            *(ux8*)&Bl[nr][kc] = *(const ux8*)&wlt[o];
        }
        __syncthreads();

        bf16x8 ah[2], al[2], bh[2], bl[2];
        #pragma unroll
        for (int m = 0; m < 2; ++m) {
            ah[m] = *(const bf16x8*)&Ah[wr * 32 + m * 16 + fr][fq * 8];
            al[m] = *(const bf16x8*)&Al[wr * 32 + m * 16 + fr][fq * 8];
        }
        #pragma unroll
        for (int n = 0; n < 2; ++n) {
            bh[n] = *(const bf16x8*)&Bh[wc * 32 + n * 16 + fr][fq * 8];
            bl[n] = *(const bf16x8*)&Bl[wc * 32 + n * 16 + fr][fq * 8];
        }
        #pragma unroll
        for (int m = 0; m < 2; ++m)
            #pragma unroll
            for (int n = 0; n < 2; ++n) {
                acc[m][n] = __builtin_amdgcn_mfma_f32_16x16x32_bf16(ah[m], bh[n], acc[m][n], 0, 0, 0);
                acc[m][n] = __builtin_amdgcn_mfma_f32_16x16x32_bf16(ah[m], bl[n], acc[m][n], 0, 0, 0);
                acc[m][n] = __builtin_amdgcn_mfma_f32_16x16x32_bf16(al[m], bh[n], acc[m][n], 0, 0, 0);
            }
        __syncthreads();
    }

    #pragma unroll
    for (int n = 0; n < 2; ++n) {
        int col = bcol + wc * 32 + n * 16 + fr;
        float bb = bproj[col];
        #pragma unroll
        for (int m = 0; m < 2; ++m) {
            int rbase = brow + wr * 32 + m * 16 + fq * 4;
            #pragma unroll
            for (int j = 0; j < 4; ++j)
                z[(size_t)(rbase + j) * TOTAL_DIM + col] = acc[m][n][j] + bb;
        }
    }
}

// ------- code / score + near-zero flagging (ballot-aggregated, sign in bit31) ----
__global__ __launch_bounds__(256)
void code_score2(const float* __restrict__ z, int* __restrict__ code,
                 float* __restrict__ score, uint32_t* __restrict__ flags,
                 uint32_t* __restrict__ cnt, int NT)
{
    int idx = blockIdx.x * 256 + threadIdx.x;
    bool live = idx < NT;
    int n = idx >> 6;
    int t = idx & 63;
    const int lane = threadIdx.x & 63;
    const float* zp = z + (size_t)n * TOTAL_DIM + t * CODE_LEN;
    float s = 1.0f;
    int   c = 0;
    #pragma unroll
    for (int i = 0; i < CODE_LEN; ++i) {
        float v = live ? zp[i] : 1.0f;
        bool  p = fabsf(v) < TAU;                   // sign uncertain under bf16x3
        unsigned long long mask = __ballot(p);
        if (mask) {                                 // one atomic per wave per i
            int nact = __popcll(mask);
            int lead = __ffsll((long long)mask) - 1;
            uint32_t base = 0;
            if (lane == lead) base = atomicAdd(cnt, (uint32_t)nact);
            base = (uint32_t)__shfl((int)base, lead);
            if (p) {
                uint32_t slot = base + (uint32_t)__popcll(mask & ((1ull << lane) - 1ull));
                if (slot < FCAP) {
                    uint32_t nd = (uint32_t)(n * TOTAL_DIM + t * CODE_LEN + i);
                    flags[slot] = nd | (v > 0.0f ? 0x80000000u : 0u);
                }
            }
        }
        s *= 0.5f * (1.0f + tanhf(fabsf(v)));
        c |= (v > 0.0f) ? (1 << i) : 0;
    }
    if (live) {
        code[idx]  = c;
        score[idx] = s;
    }
}

// ----- exact fp32 recompute of flagged z via transposed W (coalesced); fix bits ----
__global__ __launch_bounds__(256)
void fixz(const float* __restrict__ x, const float* __restrict__ wt32,
          const float* __restrict__ bproj, int* __restrict__ code,
          const uint32_t* __restrict__ flags, const uint32_t* __restrict__ cnt)
{
    const int lane = threadIdx.x & 63;
    const int gw   = (blockIdx.x * 256 + threadIdx.x) >> 6;
    const int nw   = (gridDim.x * 256) >> 6;
    uint32_t count = *cnt;
    if (count > FCAP) count = FCAP;

    for (uint32_t f = gw; f < count; f += nw) {
        uint32_t fl = flags[f];
        uint32_t e  = fl & 0x7FFFFFFFu;
        int oldpos  = (int)(fl >> 31);
        int n = e / TOTAL_DIM, d = e % TOTAL_DIM;
        const float* xr = x    + (size_t)n * HIDDEN;
        const float* wr = wt32 + (size_t)d * HIDDEN;
        float p = 0.0f;
        #pragma unroll
        for (int j = 0; j < 16; ++j) {
            int k = lane + j * 64;
            p = fmaf(xr[k], wr[k], p);
        }
        #pragma unroll
        for (int off = 32; off; off >>= 1) p += __shfl_xor(p, off);
        float v = p + bproj[d];
        if (lane == 0) {
            if ((v > 0.0f) != (oldpos != 0)) {
                int t = d / CODE_LEN, i = d % CODE_LEN;
                atomicXor(&code[n * NUM_TABLE + t], 1 << i);
            }
        }
    }
}

// ------ gather, column-grouped: block = 64 tokens x one 32-col group --------------
// btab slice per group = 4 MB (one XCD L2). g = (b&7)+8*(b>>10): blockIdx round-
// robins XCDs, so each XCD runs one group's 128 blocks per phase (4 phases).
#define TPB 64
__global__ __launch_bounds__(256)
void gather_grouped(const ushort* __restrict__ btab, const float* __restrict__ bias,
                    const int* __restrict__ code, const float* __restrict__ score,
                    float* __restrict__ out)
{
    __shared__ int   sc[TPB][NUM_TABLE + 1];
    __shared__ float sw[TPB][NUM_TABLE + 1];

    const int b   = blockIdx.x;
    const int g   = (b & 7) + 8 * (b >> 10);     // 0..31, XCD-aligned phases
    const int tch = (b >> 3) & 127;              // 128 chunks of 64 tokens
    const int n0  = tch * TPB;
    const int tid = threadIdx.x;

    for (int i = tid; i < TPB * NUM_TABLE; i += 256) {
        int tok = i >> 6, t = i & 63;
        sc[tok][t] = __builtin_nontemporal_load(&code[(n0 + tok) * NUM_TABLE + t]);
        sw[tok][t] = __builtin_nontemporal_load(&score[(n0 + tok) * NUM_TABLE + t]);
    }
    __syncthreads();

    const int tok = tid >> 2;                    // 0..63
    const int sub = tid & 3;                     // 8 cols each (16 B)
    const ushort* tbase = btab + (size_t)g * NUM_TABLE * TABLE_SZ * CPG;

    float acc[8];
    {
        const float* bp = &bias[g * CPG + sub * 8];
        #pragma unroll
        for (int j = 0; j < 8; ++j) acc[j] = bp[j];
    }

    #pragma unroll 4
    for (int t = 0; t < NUM_TABLE; ++t) {
        int   c = sc[tok][t];
        float w = sw[tok][t];
        const ux8 v = *(const ux8*)&tbase[(((size_t)t * TABLE_SZ + c) << 5) + sub * 8];
        #pragma unroll
        for (int j = 0; j < 8; ++j)
            acc[j] += w * __uint_as_float((uint32_t)v[j] << 16);
    }

    fx4 o0 = {acc[0], acc[1], acc[2], acc[3]};
    fx4 o1 = {acc[4], acc[5], acc[6], acc[7]};
    float* op = &out[(size_t)(n0 + tok) * OUTD + g * CPG + sub * 8];
    __builtin_nontemporal_store(o0, (fx4*)op);
    __builtin_nontemporal_store(o1, (fx4*)(op + 4));
}

// ---------------- fallback path (ws too small): fp32 vector GEMM + f32 gather ----
#define BM 64
#define BN 64
#define BK 32
__global__ __launch_bounds__(256)
void gemm_proj(const float* __restrict__ x, const float* __restrict__ W,
               const float* __restrict__ bproj, float* __restrict__ z)
{
    __shared__ float As[BK][BM + 4];
    __shared__ float Bs[BK][BN];
    const int tid  = threadIdx.x;
    const int brow = blockIdx.x * BM;
    const int bcol = blockIdx.y * BN;
    const int tr   = tid >> 4;
    const int tc   = tid & 15;
    float acc[4][4] = {};
    for (int k0 = 0; k0 < HIDDEN; k0 += BK) {
        #pragma unroll
        for (int i = 0; i < 2; ++i) {
            int lin = tid + i * 256;
            int r = lin >> 3, c8 = lin & 7;
            float4 a = *(const float4*)&x[(size_t)(brow + r) * HIDDEN + k0 + c8 * 4];
            As[c8 * 4 + 0][r] = a.x; As[c8 * 4 + 1][r] = a.y;
            As[c8 * 4 + 2][r] = a.z; As[c8 * 4 + 3][r] = a.w;
        }
        #pragma unroll
        for (int i = 0; i < 2; ++i) {
            int lin = tid + i * 256;
            int kk = lin >> 4, m4 = lin & 15;
            *(float4*)&Bs[kk][m4 * 4] =
                *(const float4*)&W[(size_t)(k0 + kk) * TOTAL_DIM + bcol + m4 * 4];
        }
        __syncthreads();
        #pragma unroll
        for (int kk = 0; kk < BK; ++kk) {
            float4 a = *(const float4*)&As[kk][tr * 4];
            float4 b = *(const float4*)&Bs[kk][tc * 4];
            acc[0][0] += a.x * b.x; acc[0][1] += a.x * b.y; acc[0][2] += a.x * b.z; acc[0][3] += a.x * b.w;
            acc[1][0] += a.y * b.x; acc[1][1] += a.y * b.y; acc[1][2] += a.y * b.z; acc[1][3] += a.y * b.w;
            acc[2][0] += a.z * b.x; acc[2][1] += a.z * b.y; acc[2][2] += a.z * b.z; acc[2][3] += a.z * b.w;
            acc[3][0] += a.w * b.x; acc[3][1] += a.w * b.y; acc[3][2] += a.w * b.z; acc[3][3] += a.w * b.w;
        }
        __syncthreads();
    }
    float4 bb = *(const float4*)&bproj[bcol + tc * 4];
    #pragma unroll
    for (int i = 0; i < 4; ++i) {
        int r = brow + tr * 4 + i;
        float4 o = {acc[i][0] + bb.x, acc[i][1] + bb.y, acc[i][2] + bb.z, acc[i][3] + bb.w};
        *(float4*)&z[(size_t)r * TOTAL_DIM + bcol + tc * 4] = o;
    }
}

__global__ __launch_bounds__(256)
void code_score(const float* __restrict__ z, int* __restrict__ code,
                float* __restrict__ score, int NT)
{
    int idx = blockIdx.x * 256 + threadIdx.x;
    if (idx >= NT) return;
    int n = idx >> 6, t = idx & 63;
    const float* zp = z + (size_t)n * TOTAL_DIM + t * CODE_LEN;
    float s = 1.0f; int c = 0;
    #pragma unroll
    for (int i = 0; i < CODE_LEN; ++i) {
        float v = zp[i];
        s *= 0.5f * (1.0f + tanhf(fabsf(v)));
        c |= (v > 0.0f) ? (1 << i) : 0;
    }
    code[idx] = c; score[idx] = s;
}

__global__ __launch_bounds__(256)
void gather_sum_f32(const float* __restrict__ tables, const float* __restrict__ bias,
                    const int* __restrict__ code, const float* __restrict__ score,
                    float* __restrict__ out)
{
    __shared__ int   sc[NUM_TABLE];
    __shared__ float sw[NUM_TABLE];
    const int n = blockIdx.x, tid = threadIdx.x;
    if (tid < NUM_TABLE) {
        sc[tid] = code[n * NUM_TABLE + tid];
        sw[tid] = score[n * NUM_TABLE + tid];
    }
    __syncthreads();
    float4 acc = *(const float4*)&bias[tid * 4];
    #pragma unroll 4
    for (int t = 0; t < NUM_TABLE; ++t) {
        const float* row = tables + ((size_t)(t * TABLE_SZ + sc[t])) * OUTD;
        float4 v = *(const float4*)&row[tid * 4];
        float w = sw[t];
        acc.x += v.x * w; acc.y += v.y * w; acc.z += v.z * w; acc.w += v.w * w;
    }
    *(float4*)&out[(size_t)n * OUTD + tid * 4] = acc;
}

extern "C" void kernel_launch(void* const* d_in, const int* in_sizes, int n_in,
                              void* d_out, int out_size, void* d_ws, size_t ws_size,
                              hipStream_t stream) {
    const float* x      = (const float*)d_in[0];
    const float* W      = (const float*)d_in[1];
    const float* bproj  = (const float*)d_in[2];
    const float* tables = (const float*)d_in[3];
    const float* bias   = (const float*)d_in[4];
    float* out = (float*)d_out;

    const int N = in_sizes[0] / HIDDEN;           // 8192

    // ws: z | code | score | wht | wlt | wt32 | flags | cnt | btab
    char* ws = (char*)d_ws;
    size_t off_z     = 0;
    size_t off_code  = off_z     + (size_t)N * TOTAL_DIM * sizeof(float);
    size_t off_score = off_code  + (size_t)N * NUM_TABLE * sizeof(int);
    size_t off_wht   = off_score + (size_t)N * NUM_TABLE * sizeof(float);
    size_t off_wlt   = off_wht   + (size_t)TOTAL_DIM * HIDDEN * sizeof(ushort);
    size_t off_wt32  = off_wlt   + (size_t)TOTAL_DIM * HIDDEN * sizeof(ushort);
    size_t off_flags = off_wt32  + (size_t)TOTAL_DIM * HIDDEN * sizeof(float);
    size_t off_cnt   = off_flags + (size_t)FCAP * sizeof(uint32_t);
    size_t off_btab  = (off_cnt + 4 + 255) & ~(size_t)255;
    size_t tab_elems = (size_t)NUM_TABLE * TABLE_SZ * OUTD;
    size_t need      = off_btab + tab_elems * sizeof(ushort);

    float*    z     = (float*)(ws + off_z);
    int*      code  = (int*)(ws + off_code);
    float*    score = (float*)(ws + off_score);
    ushort*   wht   = (ushort*)(ws + off_wht);
    ushort*   wlt   = (ushort*)(ws + off_wlt);
    float*    wt32  = (float*)(ws + off_wt32);
    uint32_t* flags = (uint32_t*)(ws + off_flags);
    uint32_t* cnt   = (uint32_t*)(ws + off_cnt);
    ushort*   btab  = (ushort*)(ws + off_btab);

    int NT = N * NUM_TABLE;

    if (ws_size >= need) {
        dim3 gw(TOTAL_DIM / 32, HIDDEN / 32);
        split_wt<<<gw, 256, 0, stream>>>(W, wht, wlt, wt32);
        (void)hipMemsetAsync(cnt, 0, 4, stream);

        gemm_convert<<<GEMM_BLKS + CONV_BLKS, 256, 0, stream>>>(
            x, wht, wlt, bproj, z, tables, btab);

        code_score2<<<(NT + 255) / 256, 256, 0, stream>>>(z, code, score, flags, cnt, NT);
        fixz<<<512, 256, 0, stream>>>(x, wt32, bproj, code, flags, cnt);

        gather_grouped<<<NGRP * (N / TPB), 256, 0, stream>>>(btab, bias, code, score, out);
    } else {
        dim3 g1(N / BM, TOTAL_DIM / BN);
        gemm_proj<<<g1, 256, 0, stream>>>(x, W, bproj, z);
        code_score<<<(NT + 255) / 256, 256, 0, stream>>>(z, code, score, NT);
        gather_sum_f32<<<N, 256, 0, stream>>>(tables, bias, code, score, out);
    }
}

// Round 15
// 306.703 us; speedup vs baseline: 1.5190x; 1.0602x over previous
//
#include <hip/hip_runtime.h>
#include <cstddef>
#include <cstdint>

#define HIDDEN    1024
#define OUTD      1024
#define NUM_TABLE 64
#define CODE_LEN  10
#define TABLE_SZ  1024
#define TOTAL_DIM 640

#define TAU   1e-3f
#define FCAP  131072u

typedef float  fx4    __attribute__((ext_vector_type(4)));
typedef ushort ux4    __attribute__((ext_vector_type(4)));
typedef ushort ux8    __attribute__((ext_vector_type(8)));
typedef short  bf16x8 __attribute__((ext_vector_type(8)));
typedef float  f32x4  __attribute__((ext_vector_type(4)));

// ---------- bf16 helpers (truncation split: v = hi + lo + O(2^-16 v)) ----------
struct bfp { ushort hi, lo; };
static __device__ __forceinline__ bfp split2(float v) {
    uint32_t u  = __float_as_uint(v);
    float    fh = __uint_as_float(u & 0xFFFF0000u);
    uint32_t ul = __float_as_uint(v - fh);   // exact subtraction
    bfp r; r.hi = (ushort)(u >> 16); r.lo = (ushort)(ul >> 16);
    return r;
}
static __device__ __forceinline__ ushort f2bf(float f) {   // RNE, for tables
    uint32_t u = __float_as_uint(f);
    return (ushort)((u + 0x7FFFu + ((u >> 16) & 1u)) >> 16);
}

// ---- split + transpose W: [1024][640] f32 -> wht/wlt bf16 + wt32 f32, [640][1024] ----
__global__ __launch_bounds__(256)
void split_wt(const float* __restrict__ W, ushort* __restrict__ wht,
              ushort* __restrict__ wlt, float* __restrict__ wt32)
{
    __shared__ float t[32][33];
    const int d0 = blockIdx.x * 32, k0 = blockIdx.y * 32;
    const int lx = threadIdx.x & 31, ly = threadIdx.x >> 5;   // 32 x 8
    #pragma unroll
    for (int i = 0; i < 32; i += 8)
        t[ly + i][lx] = W[(size_t)(k0 + ly + i) * TOTAL_DIM + d0 + lx];
    __syncthreads();
    #pragma unroll
    for (int i = 0; i < 32; i += 8) {
        float v = t[lx][ly + i];              // = W[k0+lx][d0+ly+i]
        bfp s = split2(v);
        size_t o = (size_t)(d0 + ly + i) * HIDDEN + k0 + lx;
        wht[o] = s.hi; wlt[o] = s.lo; wt32[o] = v;
    }
}

// ------------- fused: bf16x3 MFMA GEMM (64x64, BK=64, XOR-swz LDS) + convert -------
// GEMM blocks 0..1279: z = x @ W + b; 64x64 tile, BK=64, 4 waves (2x2), 2x2 frags.
//   LDS [64 rows][64 bf16] per tile; 16B chunk c stored at (c ^ (row&7)) -> 2-way
//   banks on both ds_write_b128 and ds_read_b128 (free, m136). 32 KB -> 5 blk/CU.
// Convert blocks 1280..2303: fp32 tables -> bf16 btab grouped [g][t][row][32c];
//   output-linear mapping: wave writes 1 KB contiguous, reads 128 B segments.
#define GBM 64
#define GBN 64
#define GBK 64
#define GEMM_MB (8192 / GBM)                    // 128
#define GEMM_NB (TOTAL_DIM / GBN)               // 10
#define GEMM_BLKS (GEMM_MB * GEMM_NB)           // 1280
#define CONV_BLKS 1024
#define CPG 32                                  // cols per group
#define NGRP (OUTD / CPG)                       // 32

__global__ __launch_bounds__(256)
void gemm_convert(const float* __restrict__ x, const ushort* __restrict__ wht,
                  const ushort* __restrict__ wlt, const float* __restrict__ bproj,
                  float* __restrict__ z,
                  const float* __restrict__ tables, ushort* __restrict__ btab)
{
    __shared__ ushort Ah[GBM * GBK];
    __shared__ ushort Al[GBM * GBK];
    __shared__ ushort Bh[GBN * GBK];
    __shared__ ushort Bl[GBN * GBK];

    const int gb  = blockIdx.x;
    const int tid = threadIdx.x;

    if (gb >= GEMM_BLKS) {
        // ---- convert path: output-linear over btab ux4s ----
        const int cb = gb - GEMM_BLKS;                  // 0..1023
        const int nj = NUM_TABLE * TABLE_SZ * (OUTD / 4);   // 16.78M
        const fx4* tp = (const fx4*)tables;
        const int stride = CONV_BLKS * 256;
        for (int j = cb * 256 + tid; j < nj; j += stride) {
            int sub = j & 7;                            // 4-col piece within group
            int row = (j >> 3) & 1023;
            int t   = (j >> 13) & 63;
            int g   = j >> 19;                          // 0..31
            fx4 v = __builtin_nontemporal_load(
                        &tp[((size_t)t * TABLE_SZ + row) * 256 + g * 8 + sub]);
            ux4 u;
            u.x = f2bf(v.x); u.y = f2bf(v.y); u.z = f2bf(v.z); u.w = f2bf(v.w);
            *(ux4*)&btab[(size_t)j * 4] = u;            // fully coalesced
        }
        return;
    }

    // ---- GEMM path ----
    const int lane = tid & 63, wid = tid >> 6;
    const int wr = wid >> 1, wc = wid & 1;             // 2x2 wave grid (32x32 each)
    const int brow = (gb % GEMM_MB) * GBM;
    const int bcol = (gb / GEMM_MB) * GBN;
    const int fr = lane & 15, fq = lane >> 4;

    f32x4 acc[2][2] = {};

    for (int k0 = 0; k0 < HIDDEN; k0 += GBK) {
        // stage A: 64 rows x 64 k fp32 -> split -> swizzled ux8 chunks
        #pragma unroll
        for (int i = 0; i < 2; ++i) {
            int idx = tid + i * 256;                   // 0..511
            int r = idx >> 3, c8 = idx & 7;            // logical 16B chunk
            const float* xp = &x[(size_t)(brow + r) * HIDDEN + k0 + c8 * 8];
            fx4 v0 = *(const fx4*)xp;
            fx4 v1 = *(const fx4*)(xp + 4);
            bfp s0 = split2(v0.x), s1 = split2(v0.y), s2 = split2(v0.z), s3 = split2(v0.w);
            bfp s4 = split2(v1.x), s5 = split2(v1.y), s6 = split2(v1.z), s7 = split2(v1.w);
            ux8 h, l;
            h[0]=s0.hi; h[1]=s1.hi; h[2]=s2.hi; h[3]=s3.hi;
            h[4]=s4.hi; h[5]=s5.hi; h[6]=s6.hi; h[7]=s7.hi;
            l[0]=s0.lo; l[1]=s1.lo; l[2]=s2.lo; l[3]=s3.lo;
            l[4]=s4.lo; l[5]=s5.lo; l[6]=s6.lo; l[7]=s7.lo;
            int so = r * GBK + (c8 ^ (r & 7)) * 8;
            *(ux8*)&Ah[so] = h;
            *(ux8*)&Al[so] = l;
        }
        // stage B^T: 64 n x 64 k bf16, swizzled ux8 copies
        #pragma unroll
        for (int i = 0; i < 2; ++i) {
            int idx = tid + i * 256;
            int nr = idx >> 3, c8 = idx & 7;
            size_t o = (size_t)(bcol + nr) * HIDDEN + k0 + c8 * 8;
            int so = nr * GBK + (c8 ^ (nr & 7)) * 8;
            *(ux8*)&Bh[so] = *(const ux8*)&wht[o];
            *(ux8*)&Bl[so] = *(const ux8*)&wlt[o];
        }
        __syncthreads();

        #pragma unroll
        for (int kk = 0; kk < 2; ++kk) {               // two K=32 slices
            bf16x8 ah[2], al[2], bh[2], bl[2];
            #pragma unroll
            for (int m = 0; m < 2; ++m) {
                int r = wr * 32 + m * 16 + fr;
                int so = r * GBK + (((kk << 2) | fq) ^ (r & 7)) * 8;
                ah[m] = *(const bf16x8*)&Ah[so];
                al[m] = *(const bf16x8*)&Al[so];
            }
            #pragma unroll
            for (int n = 0; n < 2; ++n) {
                int r = wc * 32 + n * 16 + fr;
                int so = r * GBK + (((kk << 2) | fq) ^ (r & 7)) * 8;
                bh[n] = *(const bf16x8*)&Bh[so];
                bl[n] = *(const bf16x8*)&Bl[so];
            }
            #pragma unroll
            for (int m = 0; m < 2; ++m)
                #pragma unroll
                for (int n = 0; n < 2; ++n) {
                    acc[m][n] = __builtin_amdgcn_mfma_f32_16x16x32_bf16(ah[m], bh[n], acc[m][n], 0, 0, 0);
                    acc[m][n] = __builtin_amdgcn_mfma_f32_16x16x32_bf16(ah[m], bl[n], acc[m][n], 0, 0, 0);
                    acc[m][n] = __builtin_amdgcn_mfma_f32_16x16x32_bf16(al[m], bh[n], acc[m][n], 0, 0, 0);
                }
        }
        __syncthreads();
    }

    // epilogue: +bias; C/D mapping col=lane&15, row=(lane>>4)*4+reg  [m89]
    #pragma unroll
    for (int n = 0; n < 2; ++n) {
        int col = bcol + wc * 32 + n * 16 + fr;
        float bb = bproj[col];
        #pragma unroll
        for (int m = 0; m < 2; ++m) {
            int rbase = brow + wr * 32 + m * 16 + fq * 4;
            #pragma unroll
            for (int j = 0; j < 4; ++j)
                z[(size_t)(rbase + j) * TOTAL_DIM + col] = acc[m][n][j] + bb;
        }
    }
}

// ------- code / score + near-zero flagging (ballot-aggregated, sign in bit31) ----
__global__ __launch_bounds__(256)
void code_score2(const float* __restrict__ z, int* __restrict__ code,
                 float* __restrict__ score, uint32_t* __restrict__ flags,
                 uint32_t* __restrict__ cnt, int NT)
{
    int idx = blockIdx.x * 256 + threadIdx.x;
    bool live = idx < NT;
    int n = idx >> 6;
    int t = idx & 63;
    const int lane = threadIdx.x & 63;
    const float* zp = z + (size_t)n * TOTAL_DIM + t * CODE_LEN;
    float s = 1.0f;
    int   c = 0;
    #pragma unroll
    for (int i = 0; i < CODE_LEN; ++i) {
        float v = live ? zp[i] : 1.0f;
        bool  p = fabsf(v) < TAU;                   // sign uncertain under bf16x3
        unsigned long long mask = __ballot(p);
        if (mask) {                                 // one atomic per wave per i
            int nact = __popcll(mask);
            int lead = __ffsll((long long)mask) - 1;
            uint32_t base = 0;
            if (lane == lead) base = atomicAdd(cnt, (uint32_t)nact);
            base = (uint32_t)__shfl((int)base, lead);
            if (p) {
                uint32_t slot = base + (uint32_t)__popcll(mask & ((1ull << lane) - 1ull));
                if (slot < FCAP) {
                    uint32_t nd = (uint32_t)(n * TOTAL_DIM + t * CODE_LEN + i);
                    flags[slot] = nd | (v > 0.0f ? 0x80000000u : 0u);
                }
            }
        }
        s *= 0.5f * (1.0f + tanhf(fabsf(v)));
        c |= (v > 0.0f) ? (1 << i) : 0;
    }
    if (live) {
        code[idx]  = c;
        score[idx] = s;
    }
}

// ----- exact fp32 recompute of flagged z via transposed W (coalesced); fix bits ----
__global__ __launch_bounds__(256)
void fixz(const float* __restrict__ x, const float* __restrict__ wt32,
          const float* __restrict__ bproj, int* __restrict__ code,
          const uint32_t* __restrict__ flags, const uint32_t* __restrict__ cnt)
{
    const int lane = threadIdx.x & 63;
    const int gw   = (blockIdx.x * 256 + threadIdx.x) >> 6;
    const int nw   = (gridDim.x * 256) >> 6;
    uint32_t count = *cnt;
    if (count > FCAP) count = FCAP;

    for (uint32_t f = gw; f < count; f += nw) {
        uint32_t fl = flags[f];
        uint32_t e  = fl & 0x7FFFFFFFu;
        int oldpos  = (int)(fl >> 31);
        int n = e / TOTAL_DIM, d = e % TOTAL_DIM;
        const float* xr = x    + (size_t)n * HIDDEN;
        const float* wr = wt32 + (size_t)d * HIDDEN;
        float p = 0.0f;
        #pragma unroll
        for (int j = 0; j < 16; ++j) {
            int k = lane + j * 64;
            p = fmaf(xr[k], wr[k], p);
        }
        #pragma unroll
        for (int off = 32; off; off >>= 1) p += __shfl_xor(p, off);
        float v = p + bproj[d];
        if (lane == 0) {
            if ((v > 0.0f) != (oldpos != 0)) {
                int t = d / CODE_LEN, i = d % CODE_LEN;
                atomicXor(&code[n * NUM_TABLE + t], 1 << i);
            }
        }
    }
}

// ------ gather, column-grouped: block = 64 tokens x one 32-col group --------------
// btab slice per group = 4 MB (one XCD L2). g = (b&7)+8*(b>>10): blockIdx round-
// robins XCDs, so each XCD runs one group's 128 blocks per phase (4 phases).
#define TPB 64
__global__ __launch_bounds__(256)
void gather_grouped(const ushort* __restrict__ btab, const float* __restrict__ bias,
                    const int* __restrict__ code, const float* __restrict__ score,
                    float* __restrict__ out)
{
    __shared__ int   sc[TPB][NUM_TABLE + 1];
    __shared__ float sw[TPB][NUM_TABLE + 1];

    const int b   = blockIdx.x;
    const int g   = (b & 7) + 8 * (b >> 10);     // 0..31, XCD-aligned phases
    const int tch = (b >> 3) & 127;              // 128 chunks of 64 tokens
    const int n0  = tch * TPB;
    const int tid = threadIdx.x;

    for (int i = tid; i < TPB * NUM_TABLE; i += 256) {
        int tok = i >> 6, t = i & 63;
        sc[tok][t] = __builtin_nontemporal_load(&code[(n0 + tok) * NUM_TABLE + t]);
        sw[tok][t] = __builtin_nontemporal_load(&score[(n0 + tok) * NUM_TABLE + t]);
    }
    __syncthreads();

    const int tok = tid >> 2;                    // 0..63
    const int sub = tid & 3;                     // 8 cols each (16 B)
    const ushort* tbase = btab + (size_t)g * NUM_TABLE * TABLE_SZ * CPG;

    float acc[8];
    {
        const float* bp = &bias[g * CPG + sub * 8];
        #pragma unroll
        for (int j = 0; j < 8; ++j) acc[j] = bp[j];
    }

    #pragma unroll 4
    for (int t = 0; t < NUM_TABLE; ++t) {
        int   c = sc[tok][t];
        float w = sw[tok][t];
        const ux8 v = *(const ux8*)&tbase[(((size_t)t * TABLE_SZ + c) << 5) + sub * 8];
        #pragma unroll
        for (int j = 0; j < 8; ++j)
            acc[j] += w * __uint_as_float((uint32_t)v[j] << 16);
    }

    fx4 o0 = {acc[0], acc[1], acc[2], acc[3]};
    fx4 o1 = {acc[4], acc[5], acc[6], acc[7]};
    float* op = &out[(size_t)(n0 + tok) * OUTD + g * CPG + sub * 8];
    __builtin_nontemporal_store(o0, (fx4*)op);
    __builtin_nontemporal_store(o1, (fx4*)(op + 4));
}

// ---------------- fallback path (ws too small): fp32 vector GEMM + f32 gather ----
#define BM 64
#define BN 64
#define BK 32
__global__ __launch_bounds__(256)
void gemm_proj(const float* __restrict__ x, const float* __restrict__ W,
               const float* __restrict__ bproj, float* __restrict__ z)
{
    __shared__ float As[BK][BM + 4];
    __shared__ float Bs[BK][BN];
    const int tid  = threadIdx.x;
    const int brow = blockIdx.x * BM;
    const int bcol = blockIdx.y * BN;
    const int tr   = tid >> 4;
    const int tc   = tid & 15;
    float acc[4][4] = {};
    for (int k0 = 0; k0 < HIDDEN; k0 += BK) {
        #pragma unroll
        for (int i = 0; i < 2; ++i) {
            int lin = tid + i * 256;
            int r = lin >> 3, c8 = lin & 7;
            float4 a = *(const float4*)&x[(size_t)(brow + r) * HIDDEN + k0 + c8 * 4];
            As[c8 * 4 + 0][r] = a.x; As[c8 * 4 + 1][r] = a.y;
            As[c8 * 4 + 2][r] = a.z; As[c8 * 4 + 3][r] = a.w;
        }
        #pragma unroll
        for (int i = 0; i < 2; ++i) {
            int lin = tid + i * 256;
            int kk = lin >> 4, m4 = lin & 15;
            *(float4*)&Bs[kk][m4 * 4] =
                *(const float4*)&W[(size_t)(k0 + kk) * TOTAL_DIM + bcol + m4 * 4];
        }
        __syncthreads();
        #pragma unroll
        for (int kk = 0; kk < BK; ++kk) {
            float4 a = *(const float4*)&As[kk][tr * 4];
            float4 b = *(const float4*)&Bs[kk][tc * 4];
            acc[0][0] += a.x * b.x; acc[0][1] += a.x * b.y; acc[0][2] += a.x * b.z; acc[0][3] += a.x * b.w;
            acc[1][0] += a.y * b.x; acc[1][1] += a.y * b.y; acc[1][2] += a.y * b.z; acc[1][3] += a.y * b.w;
            acc[2][0] += a.z * b.x; acc[2][1] += a.z * b.y; acc[2][2] += a.z * b.z; acc[2][3] += a.z * b.w;
            acc[3][0] += a.w * b.x; acc[3][1] += a.w * b.y; acc[3][2] += a.w * b.z; acc[3][3] += a.w * b.w;
        }
        __syncthreads();
    }
    float4 bb = *(const float4*)&bproj[bcol + tc * 4];
    #pragma unroll
    for (int i = 0; i < 4; ++i) {
        int r = brow + tr * 4 + i;
        float4 o = {acc[i][0] + bb.x, acc[i][1] + bb.y, acc[i][2] + bb.z, acc[i][3] + bb.w};
        *(float4*)&z[(size_t)r * TOTAL_DIM + bcol + tc * 4] = o;
    }
}

__global__ __launch_bounds__(256)
void code_score(const float* __restrict__ z, int* __restrict__ code,
                float* __restrict__ score, int NT)
{
    int idx = blockIdx.x * 256 + threadIdx.x;
    if (idx >= NT) return;
    int n = idx >> 6, t = idx & 63;
    const float* zp = z + (size_t)n * TOTAL_DIM + t * CODE_LEN;
    float s = 1.0f; int c = 0;
    #pragma unroll
    for (int i = 0; i < CODE_LEN; ++i) {
        float v = zp[i];
        s *= 0.5f * (1.0f + tanhf(fabsf(v)));
        c |= (v > 0.0f) ? (1 << i) : 0;
    }
    code[idx] = c; score[idx] = s;
}

__global__ __launch_bounds__(256)
void gather_sum_f32(const float* __restrict__ tables, const float* __restrict__ bias,
                    const int* __restrict__ code, const float* __restrict__ score,
                    float* __restrict__ out)
{
    __shared__ int   sc[NUM_TABLE];
    __shared__ float sw[NUM_TABLE];
    const int n = blockIdx.x, tid = threadIdx.x;
    if (tid < NUM_TABLE) {
        sc[tid] = code[n * NUM_TABLE + tid];
        sw[tid] = score[n * NUM_TABLE + tid];
    }
    __syncthreads();
    float4 acc = *(const float4*)&bias[tid * 4];
    #pragma unroll 4
    for (int t = 0; t < NUM_TABLE; ++t) {
        const float* row = tables + ((size_t)(t * TABLE_SZ + sc[t])) * OUTD;
        float4 v = *(const float4*)&row[tid * 4];
        float w = sw[t];
        acc.x += v.x * w; acc.y += v.y * w; acc.z += v.z * w; acc.w += v.w * w;
    }
    *(float4*)&out[(size_t)n * OUTD + tid * 4] = acc;
}

extern "C" void kernel_launch(void* const* d_in, const int* in_sizes, int n_in,
                              void* d_out, int out_size, void* d_ws, size_t ws_size,
                              hipStream_t stream) {
    const float* x      = (const float*)d_in[0];
    const float* W      = (const float*)d_in[1];
    const float* bproj  = (const float*)d_in[2];
    const float* tables = (const float*)d_in[3];
    const float* bias   = (const float*)d_in[4];
    float* out = (float*)d_out;

    const int N = in_sizes[0] / HIDDEN;           // 8192

    // ws: z | code | score | wht | wlt | wt32 | flags | cnt | btab
    char* ws = (char*)d_ws;
    size_t off_z     = 0;
    size_t off_code  = off_z     + (size_t)N * TOTAL_DIM * sizeof(float);
    size_t off_score = off_code  + (size_t)N * NUM_TABLE * sizeof(int);
    size_t off_wht   = off_score + (size_t)N * NUM_TABLE * sizeof(float);
    size_t off_wlt   = off_wht   + (size_t)TOTAL_DIM * HIDDEN * sizeof(ushort);
    size_t off_wt32  = off_wlt   + (size_t)TOTAL_DIM * HIDDEN * sizeof(ushort);
    size_t off_flags = off_wt32  + (size_t)TOTAL_DIM * HIDDEN * sizeof(float);
    size_t off_cnt   = off_flags + (size_t)FCAP * sizeof(uint32_t);
    size_t off_btab  = (off_cnt + 4 + 255) & ~(size_t)255;
    size_t tab_elems = (size_t)NUM_TABLE * TABLE_SZ * OUTD;
    size_t need      = off_btab + tab_elems * sizeof(ushort);

    float*    z     = (float*)(ws + off_z);
    int*      code  = (int*)(ws + off_code);
    float*    score = (float*)(ws + off_score);
    ushort*   wht   = (ushort*)(ws + off_wht);
    ushort*   wlt   = (ushort*)(ws + off_wlt);
    float*    wt32  = (float*)(ws + off_wt32);
    uint32_t* flags = (uint32_t*)(ws + off_flags);
    uint32_t* cnt   = (uint32_t*)(ws + off_cnt);
    ushort*   btab  = (ushort*)(ws + off_btab);

    int NT = N * NUM_TABLE;

    if (ws_size >= need) {
        dim3 gw(TOTAL_DIM / 32, HIDDEN / 32);
        split_wt<<<gw, 256, 0, stream>>>(W, wht, wlt, wt32);
        (void)hipMemsetAsync(cnt, 0, 4, stream);

        gemm_convert<<<GEMM_BLKS + CONV_BLKS, 256, 0, stream>>>(
            x, wht, wlt, bproj, z, tables, btab);

        code_score2<<<(NT + 255) / 256, 256, 0, stream>>>(z, code, score, flags, cnt, NT);
        fixz<<<512, 256, 0, stream>>>(x, wt32, bproj, code, flags, cnt);

        gather_grouped<<<NGRP * (N / TPB), 256, 0, stream>>>(btab, bias, code, score, out);
    } else {
        dim3 g1(N / BM, TOTAL_DIM / BN);
        gemm_proj<<<g1, 256, 0, stream>>>(x, W, bproj, z);
        code_score<<<(NT + 255) / 256, 256, 0, stream>>>(z, code, score, NT);
        gather_sum_f32<<<N, 256, 0, stream>>>(tables, bias, code, score, out);
    }
}

// Round 17
// 306.259 us; speedup vs baseline: 1.5212x; 1.0014x over previous
//
#include <hip/hip_runtime.h>
#include <cstddef>
#include <cstdint>

#define HIDDEN    1024
#define OUTD      1024
#define NUM_TABLE 64
#define CODE_LEN  10
#define TABLE_SZ  1024
#define TOTAL_DIM 640

#define TAU   1e-3f
#define FCAP  131072u

typedef float  fx4    __attribute__((ext_vector_type(4)));
typedef ushort ux4    __attribute__((ext_vector_type(4)));
typedef ushort ux8    __attribute__((ext_vector_type(8)));
typedef short  bf16x8 __attribute__((ext_vector_type(8)));
typedef float  f32x4  __attribute__((ext_vector_type(4)));

// ---------- bf16 helpers (truncation split: v = hi + lo + O(2^-16 v)) ----------
struct bfp { ushort hi, lo; };
static __device__ __forceinline__ bfp split2(float v) {
    uint32_t u  = __float_as_uint(v);
    float    fh = __uint_as_float(u & 0xFFFF0000u);
    uint32_t ul = __float_as_uint(v - fh);   // exact subtraction
    bfp r; r.hi = (ushort)(u >> 16); r.lo = (ushort)(ul >> 16);
    return r;
}
static __device__ __forceinline__ ushort f2bf(float f) {   // RNE, for tables
    uint32_t u = __float_as_uint(f);
    return (ushort)((u + 0x7FFFu + ((u >> 16) & 1u)) >> 16);
}

// ---- split + transpose W: [1024][640] f32 -> wht/wlt bf16 + wt32 f32, [640][1024] ----
__global__ __launch_bounds__(256)
void split_wt(const float* __restrict__ W, ushort* __restrict__ wht,
              ushort* __restrict__ wlt, float* __restrict__ wt32)
{
    __shared__ float t[32][33];
    const int d0 = blockIdx.x * 32, k0 = blockIdx.y * 32;
    const int lx = threadIdx.x & 31, ly = threadIdx.x >> 5;   // 32 x 8
    #pragma unroll
    for (int i = 0; i < 32; i += 8)
        t[ly + i][lx] = W[(size_t)(k0 + ly + i) * TOTAL_DIM + d0 + lx];
    __syncthreads();
    #pragma unroll
    for (int i = 0; i < 32; i += 8) {
        float v = t[lx][ly + i];              // = W[k0+lx][d0+ly+i]
        bfp s = split2(v);
        size_t o = (size_t)(d0 + ly + i) * HIDDEN + k0 + lx;
        wht[o] = s.hi; wlt[o] = s.lo; wt32[o] = v;
    }
}

// ------------- fused: bf16x3 MFMA GEMM (64x64, BK=64, XOR-swz LDS) + convert -------
// GEMM blocks 0..1279: z = x @ W + b; 64x64 tile, BK=64, 4 waves (2x2), 2x2 frags.
//   LDS [64 rows][64 bf16] per tile; 16B chunk c stored at (c ^ (row&7)) -> 2-way
//   banks on both ds_write_b128 and ds_read_b128 (free, m136). 32 KB -> 5 blk/CU.
// Convert blocks 1280..2303: fp32 tables -> bf16 btab grouped [g][t][row][32c];
//   output-linear mapping: wave writes 1 KB contiguous, reads 128 B segments.
#define GBM 64
#define GBN 64
#define GBK 64
#define GEMM_MB (8192 / GBM)                    // 128
#define GEMM_NB (TOTAL_DIM / GBN)               // 10
#define GEMM_BLKS (GEMM_MB * GEMM_NB)           // 1280
#define CONV_BLKS 1024
#define CPG 32                                  // cols per group
#define NGRP (OUTD / CPG)                       // 32

__global__ __launch_bounds__(256)
void gemm_convert(const float* __restrict__ x, const ushort* __restrict__ wht,
                  const ushort* __restrict__ wlt, const float* __restrict__ bproj,
                  float* __restrict__ z,
                  const float* __restrict__ tables, ushort* __restrict__ btab)
{
    __shared__ ushort Ah[GBM * GBK];
    __shared__ ushort Al[GBM * GBK];
    __shared__ ushort Bh[GBN * GBK];
    __shared__ ushort Bl[GBN * GBK];

    const int gb  = blockIdx.x;
    const int tid = threadIdx.x;

    if (gb >= GEMM_BLKS) {
        // ---- convert path: output-linear over btab ux4s ----
        const int cb = gb - GEMM_BLKS;                  // 0..1023
        const int nj = NUM_TABLE * TABLE_SZ * (OUTD / 4);   // 16.78M
        const fx4* tp = (const fx4*)tables;
        const int stride = CONV_BLKS * 256;
        for (int j = cb * 256 + tid; j < nj; j += stride) {
            int sub = j & 7;                            // 4-col piece within group
            int row = (j >> 3) & 1023;
            int t   = (j >> 13) & 63;
            int g   = j >> 19;                          // 0..31
            fx4 v = __builtin_nontemporal_load(
                        &tp[((size_t)t * TABLE_SZ + row) * 256 + g * 8 + sub]);
            ux4 u;
            u.x = f2bf(v.x); u.y = f2bf(v.y); u.z = f2bf(v.z); u.w = f2bf(v.w);
            *(ux4*)&btab[(size_t)j * 4] = u;            // fully coalesced
        }
        return;
    }

    // ---- GEMM path ----
    const int lane = tid & 63, wid = tid >> 6;
    const int wr = wid >> 1, wc = wid & 1;             // 2x2 wave grid (32x32 each)
    const int brow = (gb % GEMM_MB) * GBM;
    const int bcol = (gb / GEMM_MB) * GBN;
    const int fr = lane & 15, fq = lane >> 4;

    f32x4 acc[2][2] = {};

    for (int k0 = 0; k0 < HIDDEN; k0 += GBK) {
        // stage A: 64 rows x 64 k fp32 -> split -> swizzled ux8 chunks
        #pragma unroll
        for (int i = 0; i < 2; ++i) {
            int idx = tid + i * 256;                   // 0..511
            int r = idx >> 3, c8 = idx & 7;            // logical 16B chunk
            const float* xp = &x[(size_t)(brow + r) * HIDDEN + k0 + c8 * 8];
            fx4 v0 = *(const fx4*)xp;
            fx4 v1 = *(const fx4*)(xp + 4);
            bfp s0 = split2(v0.x), s1 = split2(v0.y), s2 = split2(v0.z), s3 = split2(v0.w);
            bfp s4 = split2(v1.x), s5 = split2(v1.y), s6 = split2(v1.z), s7 = split2(v1.w);
            ux8 h, l;
            h[0]=s0.hi; h[1]=s1.hi; h[2]=s2.hi; h[3]=s3.hi;
            h[4]=s4.hi; h[5]=s5.hi; h[6]=s6.hi; h[7]=s7.hi;
            l[0]=s0.lo; l[1]=s1.lo; l[2]=s2.lo; l[3]=s3.lo;
            l[4]=s4.lo; l[5]=s5.lo; l[6]=s6.lo; l[7]=s7.lo;
            int so = r * GBK + (c8 ^ (r & 7)) * 8;
            *(ux8*)&Ah[so] = h;
            *(ux8*)&Al[so] = l;
        }
        // stage B^T: 64 n x 64 k bf16, swizzled ux8 copies
        #pragma unroll
        for (int i = 0; i < 2; ++i) {
            int idx = tid + i * 256;
            int nr = idx >> 3, c8 = idx & 7;
            size_t o = (size_t)(bcol + nr) * HIDDEN + k0 + c8 * 8;
            int so = nr * GBK + (c8 ^ (nr & 7)) * 8;
            *(ux8*)&Bh[so] = *(const ux8*)&wht[o];
            *(ux8*)&Bl[so] = *(const ux8*)&wlt[o];
        }
        __syncthreads();

        #pragma unroll
        for (int kk = 0; kk < 2; ++kk) {               // two K=32 slices
            bf16x8 ah[2], al[2], bh[2], bl[2];
            #pragma unroll
            for (int m = 0; m < 2; ++m) {
                int r = wr * 32 + m * 16 + fr;
                int so = r * GBK + (((kk << 2) | fq) ^ (r & 7)) * 8;
                ah[m] = *(const bf16x8*)&Ah[so];
                al[m] = *(const bf16x8*)&Al[so];
            }
            #pragma unroll
            for (int n = 0; n < 2; ++n) {
                int r = wc * 32 + n * 16 + fr;
                int so = r * GBK + (((kk << 2) | fq) ^ (r & 7)) * 8;
                bh[n] = *(const bf16x8*)&Bh[so];
                bl[n] = *(const bf16x8*)&Bl[so];
            }
            #pragma unroll
            for (int m = 0; m < 2; ++m)
                #pragma unroll
                for (int n = 0; n < 2; ++n) {
                    acc[m][n] = __builtin_amdgcn_mfma_f32_16x16x32_bf16(ah[m], bh[n], acc[m][n], 0, 0, 0);
                    acc[m][n] = __builtin_amdgcn_mfma_f32_16x16x32_bf16(ah[m], bl[n], acc[m][n], 0, 0, 0);
                    acc[m][n] = __builtin_amdgcn_mfma_f32_16x16x32_bf16(al[m], bh[n], acc[m][n], 0, 0, 0);
                }
        }
        __syncthreads();
    }

    // epilogue: +bias; C/D mapping col=lane&15, row=(lane>>4)*4+reg  [m89]
    #pragma unroll
    for (int n = 0; n < 2; ++n) {
        int col = bcol + wc * 32 + n * 16 + fr;
        float bb = bproj[col];
        #pragma unroll
        for (int m = 0; m < 2; ++m) {
            int rbase = brow + wr * 32 + m * 16 + fq * 4;
            #pragma unroll
            for (int j = 0; j < 4; ++j)
                z[(size_t)(rbase + j) * TOTAL_DIM + col] = acc[m][n][j] + bb;
        }
    }
}

// ------- code / score + near-zero flagging (ballot-aggregated, sign in bit31) ----
__global__ __launch_bounds__(256)
void code_score2(const float* __restrict__ z, int* __restrict__ code,
                 float* __restrict__ score, uint32_t* __restrict__ flags,
                 uint32_t* __restrict__ cnt, int NT)
{
    int idx = blockIdx.x * 256 + threadIdx.x;
    bool live = idx < NT;
    int n = idx >> 6;
    int t = idx & 63;
    const int lane = threadIdx.x & 63;
    const float* zp = z + (size_t)n * TOTAL_DIM + t * CODE_LEN;
    float s = 1.0f;
    int   c = 0;
    #pragma unroll
    for (int i = 0; i < CODE_LEN; ++i) {
        float v = live ? zp[i] : 1.0f;
        bool  p = fabsf(v) < TAU;                   // sign uncertain under bf16x3
        unsigned long long mask = __ballot(p);
        if (mask) {                                 // one atomic per wave per i
            int nact = __popcll(mask);
            int lead = __ffsll((long long)mask) - 1;
            uint32_t base = 0;
            if (lane == lead) base = atomicAdd(cnt, (uint32_t)nact);
            base = (uint32_t)__shfl((int)base, lead);
            if (p) {
                uint32_t slot = base + (uint32_t)__popcll(mask & ((1ull << lane) - 1ull));
                if (slot < FCAP) {
                    uint32_t nd = (uint32_t)(n * TOTAL_DIM + t * CODE_LEN + i);
                    flags[slot] = nd | (v > 0.0f ? 0x80000000u : 0u);
                }
            }
        }
        s *= 0.5f * (1.0f + tanhf(fabsf(v)));
        c |= (v > 0.0f) ? (1 << i) : 0;
    }
    if (live) {
        code[idx]  = c;
        score[idx] = s;
    }
}

// ----- exact fp32 recompute of flagged z via transposed W (coalesced); fix bits ----
__global__ __launch_bounds__(256)
void fixz(const float* __restrict__ x, const float* __restrict__ wt32,
          const float* __restrict__ bproj, int* __restrict__ code,
          const uint32_t* __restrict__ flags, const uint32_t* __restrict__ cnt)
{
    const int lane = threadIdx.x & 63;
    const int gw   = (blockIdx.x * 256 + threadIdx.x) >> 6;
    const int nw   = (gridDim.x * 256) >> 6;
    uint32_t count = *cnt;
    if (count > FCAP) count = FCAP;

    for (uint32_t f = gw; f < count; f += nw) {
        uint32_t fl = flags[f];
        uint32_t e  = fl & 0x7FFFFFFFu;
        int oldpos  = (int)(fl >> 31);
        int n = e / TOTAL_DIM, d = e % TOTAL_DIM;
        const float* xr = x    + (size_t)n * HIDDEN;
        const float* wr = wt32 + (size_t)d * HIDDEN;
        float p = 0.0f;
        #pragma unroll
        for (int j = 0; j < 16; ++j) {
            int k = lane + j * 64;
            p = fmaf(xr[k], wr[k], p);
        }
        #pragma unroll
        for (int off = 32; off; off >>= 1) p += __shfl_xor(p, off);
        float v = p + bproj[d];
        if (lane == 0) {
            if ((v > 0.0f) != (oldpos != 0)) {
                int t = d / CODE_LEN, i = d % CODE_LEN;
                atomicXor(&code[n * NUM_TABLE + t], 1 << i);
            }
        }
    }
}

// ------ gather, column-grouped: block = 64 tokens x one 32-col group --------------
// btab slice per group = 4 MB (one XCD L2). g = (b&7)+8*(b>>10): blockIdx round-
// robins XCDs, so each XCD runs one group's 128 blocks per phase (4 phases).
#define TPB 64
__global__ __launch_bounds__(256)
void gather_grouped(const ushort* __restrict__ btab, const float* __restrict__ bias,
                    const int* __restrict__ code, const float* __restrict__ score,
                    float* __restrict__ out)
{
    __shared__ int   sc[TPB][NUM_TABLE + 1];
    __shared__ float sw[TPB][NUM_TABLE + 1];

    const int b   = blockIdx.x;
    const int g   = (b & 7) + 8 * (b >> 10);     // 0..31, XCD-aligned phases
    const int tch = (b >> 3) & 127;              // 128 chunks of 64 tokens
    const int n0  = tch * TPB;
    const int tid = threadIdx.x;

    for (int i = tid; i < TPB * NUM_TABLE; i += 256) {
        int tok = i >> 6, t = i & 63;
        sc[tok][t] = __builtin_nontemporal_load(&code[(n0 + tok) * NUM_TABLE + t]);
        sw[tok][t] = __builtin_nontemporal_load(&score[(n0 + tok) * NUM_TABLE + t]);
    }
    __syncthreads();

    const int tok = tid >> 2;                    // 0..63
    const int sub = tid & 3;                     // 8 cols each (16 B)
    const ushort* tbase = btab + (size_t)g * NUM_TABLE * TABLE_SZ * CPG;

    float acc[8];
    {
        const float* bp = &bias[g * CPG + sub * 8];
        #pragma unroll
        for (int j = 0; j < 8; ++j) acc[j] = bp[j];
    }

    #pragma unroll 4
    for (int t = 0; t < NUM_TABLE; ++t) {
        int   c = sc[tok][t];
        float w = sw[tok][t];
        const ux8 v = *(const ux8*)&tbase[(((size_t)t * TABLE_SZ + c) << 5) + sub * 8];
        #pragma unroll
        for (int j = 0; j < 8; ++j)
            acc[j] += w * __uint_as_float((uint32_t)v[j] << 16);
    }

    fx4 o0 = {acc[0], acc[1], acc[2], acc[3]};
    fx4 o1 = {acc[4], acc[5], acc[6], acc[7]};
    float* op = &out[(size_t)(n0 + tok) * OUTD + g * CPG + sub * 8];
    __builtin_nontemporal_store(o0, (fx4*)op);
    __builtin_nontemporal_store(o1, (fx4*)(op + 4));
}

// ---------------- fallback path (ws too small): fp32 vector GEMM + f32 gather ----
#define BM 64
#define BN 64
#define BK 32
__global__ __launch_bounds__(256)
void gemm_proj(const float* __restrict__ x, const float* __restrict__ W,
               const float* __restrict__ bproj, float* __restrict__ z)
{
    __shared__ float As[BK][BM + 4];
    __shared__ float Bs[BK][BN];
    const int tid  = threadIdx.x;
    const int brow = blockIdx.x * BM;
    const int bcol = blockIdx.y * BN;
    const int tr   = tid >> 4;
    const int tc   = tid & 15;
    float acc[4][4] = {};
    for (int k0 = 0; k0 < HIDDEN; k0 += BK) {
        #pragma unroll
        for (int i = 0; i < 2; ++i) {
            int lin = tid + i * 256;
            int r = lin >> 3, c8 = lin & 7;
            float4 a = *(const float4*)&x[(size_t)(brow + r) * HIDDEN + k0 + c8 * 4];
            As[c8 * 4 + 0][r] = a.x; As[c8 * 4 + 1][r] = a.y;
            As[c8 * 4 + 2][r] = a.z; As[c8 * 4 + 3][r] = a.w;
        }
        #pragma unroll
        for (int i = 0; i < 2; ++i) {
            int lin = tid + i * 256;
            int kk = lin >> 4, m4 = lin & 15;
            *(float4*)&Bs[kk][m4 * 4] =
                *(const float4*)&W[(size_t)(k0 + kk) * TOTAL_DIM + bcol + m4 * 4];
        }
        __syncthreads();
        #pragma unroll
        for (int kk = 0; kk < BK; ++kk) {
            float4 a = *(const float4*)&As[kk][tr * 4];
            float4 b = *(const float4*)&Bs[kk][tc * 4];
            acc[0][0] += a.x * b.x; acc[0][1] += a.x * b.y; acc[0][2] += a.x * b.z; acc[0][3] += a.x * b.w;
            acc[1][0] += a.y * b.x; acc[1][1] += a.y * b.y; acc[1][2] += a.y * b.z; acc[1][3] += a.y * b.w;
            acc[2][0] += a.z * b.x; acc[2][1] += a.z * b.y; acc[2][2] += a.z * b.z; acc[2][3] += a.z * b.w;
            acc[3][0] += a.w * b.x; acc[3][1] += a.w * b.y; acc[3][2] += a.w * b.z; acc[3][3] += a.w * b.w;
        }
        __syncthreads();
    }
    float4 bb = *(const float4*)&bproj[bcol + tc * 4];
    #pragma unroll
    for (int i = 0; i < 4; ++i) {
        int r = brow + tr * 4 + i;
        float4 o = {acc[i][0] + bb.x, acc[i][1] + bb.y, acc[i][2] + bb.z, acc[i][3] + bb.w};
        *(float4*)&z[(size_t)r * TOTAL_DIM + bcol + tc * 4] = o;
    }
}

__global__ __launch_bounds__(256)
void code_score(const float* __restrict__ z, int* __restrict__ code,
                float* __restrict__ score, int NT)
{
    int idx = blockIdx.x * 256 + threadIdx.x;
    if (idx >= NT) return;
    int n = idx >> 6, t = idx & 63;
    const float* zp = z + (size_t)n * TOTAL_DIM + t * CODE_LEN;
    float s = 1.0f; int c = 0;
    #pragma unroll
    for (int i = 0; i < CODE_LEN; ++i) {
        float v = zp[i];
        s *= 0.5f * (1.0f + tanhf(fabsf(v)));
        c |= (v > 0.0f) ? (1 << i) : 0;
    }
    code[idx] = c; score[idx] = s;
}

__global__ __launch_bounds__(256)
void gather_sum_f32(const float* __restrict__ tables, const float* __restrict__ bias,
                    const int* __restrict__ code, const float* __restrict__ score,
                    float* __restrict__ out)
{
    __shared__ int   sc[NUM_TABLE];
    __shared__ float sw[NUM_TABLE];
    const int n = blockIdx.x, tid = threadIdx.x;
    if (tid < NUM_TABLE) {
        sc[tid] = code[n * NUM_TABLE + tid];
        sw[tid] = score[n * NUM_TABLE + tid];
    }
    __syncthreads();
    float4 acc = *(const float4*)&bias[tid * 4];
    #pragma unroll 4
    for (int t = 0; t < NUM_TABLE; ++t) {
        const float* row = tables + ((size_t)(t * TABLE_SZ + sc[t])) * OUTD;
        float4 v = *(const float4*)&row[tid * 4];
        float w = sw[t];
        acc.x += v.x * w; acc.y += v.y * w; acc.z += v.z * w; acc.w += v.w * w;
    }
    *(float4*)&out[(size_t)n * OUTD + tid * 4] = acc;
}

extern "C" void kernel_launch(void* const* d_in, const int* in_sizes, int n_in,
                              void* d_out, int out_size, void* d_ws, size_t ws_size,
                              hipStream_t stream) {
    const float* x      = (const float*)d_in[0];
    const float* W      = (const float*)d_in[1];
    const float* bproj  = (const float*)d_in[2];
    const float* tables = (const float*)d_in[3];
    const float* bias   = (const float*)d_in[4];
    float* out = (float*)d_out;

    const int N = in_sizes[0] / HIDDEN;           // 8192

    // ws: z | code | score | wht | wlt | wt32 | flags | cnt | btab
    char* ws = (char*)d_ws;
    size_t off_z     = 0;
    size_t off_code  = off_z     + (size_t)N * TOTAL_DIM * sizeof(float);
    size_t off_score = off_code  + (size_t)N * NUM_TABLE * sizeof(int);
    size_t off_wht   = off_score + (size_t)N * NUM_TABLE * sizeof(float);
    size_t off_wlt   = off_wht   + (size_t)TOTAL_DIM * HIDDEN * sizeof(ushort);
    size_t off_wt32  = off_wlt   + (size_t)TOTAL_DIM * HIDDEN * sizeof(ushort);
    size_t off_flags = off_wt32  + (size_t)TOTAL_DIM * HIDDEN * sizeof(float);
    size_t off_cnt   = off_flags + (size_t)FCAP * sizeof(uint32_t);
    size_t off_btab  = (off_cnt + 4 + 255) & ~(size_t)255;
    size_t tab_elems = (size_t)NUM_TABLE * TABLE_SZ * OUTD;
    size_t need      = off_btab + tab_elems * sizeof(ushort);

    float*    z     = (float*)(ws + off_z);
    int*      code  = (int*)(ws + off_code);
    float*    score = (float*)(ws + off_score);
    ushort*   wht   = (ushort*)(ws + off_wht);
    ushort*   wlt   = (ushort*)(ws + off_wlt);
    float*    wt32  = (float*)(ws + off_wt32);
    uint32_t* flags = (uint32_t*)(ws + off_flags);
    uint32_t* cnt   = (uint32_t*)(ws + off_cnt);
    ushort*   btab  = (ushort*)(ws + off_btab);

    int NT = N * NUM_TABLE;

    if (ws_size >= need) {
        dim3 gw(TOTAL_DIM / 32, HIDDEN / 32);
        split_wt<<<gw, 256, 0, stream>>>(W, wht, wlt, wt32);
        (void)hipMemsetAsync(cnt, 0, 4, stream);

        gemm_convert<<<GEMM_BLKS + CONV_BLKS, 256, 0, stream>>>(
            x, wht, wlt, bproj, z, tables, btab);

        code_score2<<<(NT + 255) / 256, 256, 0, stream>>>(z, code, score, flags, cnt, NT);
        fixz<<<1024, 256, 0, stream>>>(x, wt32, bproj, code, flags, cnt);

        gather_grouped<<<NGRP * (N / TPB), 256, 0, stream>>>(btab, bias, code, score, out);
    } else {
        dim3 g1(N / BM, TOTAL_DIM / BN);
        gemm_proj<<<g1, 256, 0, stream>>>(x, W, bproj, z);
        code_score<<<(NT + 255) / 256, 256, 0, stream>>>(z, code, score, NT);
        gather_sum_f32<<<N, 256, 0, stream>>>(tables, bias, code, score, out);
    }
}

// Round 18
// 282.951 us; speedup vs baseline: 1.6465x; 1.0824x over previous
//
#include <hip/hip_runtime.h>
#include <cstddef>
#include <cstdint>

#define HIDDEN    1024
#define OUTD      1024
#define NUM_TABLE 64
#define CODE_LEN  10
#define TABLE_SZ  1024
#define TOTAL_DIM 640

#define TAU   1e-3f
#define FCAP  131072u

typedef float  fx4    __attribute__((ext_vector_type(4)));
typedef ushort ux4    __attribute__((ext_vector_type(4)));
typedef ushort ux8    __attribute__((ext_vector_type(8)));
typedef short  bf16x8 __attribute__((ext_vector_type(8)));
typedef float  f32x4  __attribute__((ext_vector_type(4)));

// ---------- bf16 helpers (truncation split: v = hi + lo + O(2^-16 v)) ----------
struct bfp { ushort hi, lo; };
static __device__ __forceinline__ bfp split2(float v) {
    uint32_t u  = __float_as_uint(v);
    float    fh = __uint_as_float(u & 0xFFFF0000u);
    uint32_t ul = __float_as_uint(v - fh);   // exact subtraction
    bfp r; r.hi = (ushort)(u >> 16); r.lo = (ushort)(ul >> 16);
    return r;
}
static __device__ __forceinline__ ushort f2bf(float f) {   // RNE, for tables
    uint32_t u = __float_as_uint(f);
    return (ushort)((u + 0x7FFFu + ((u >> 16) & 1u)) >> 16);
}

// ---- split + transpose W: [1024][640] f32 -> wht/wlt bf16 + wt32 f32, [640][1024] ----
__global__ __launch_bounds__(256)
void split_wt(const float* __restrict__ W, ushort* __restrict__ wht,
              ushort* __restrict__ wlt, float* __restrict__ wt32)
{
    __shared__ float t[32][33];
    const int d0 = blockIdx.x * 32, k0 = blockIdx.y * 32;
    const int lx = threadIdx.x & 31, ly = threadIdx.x >> 5;   // 32 x 8
    #pragma unroll
    for (int i = 0; i < 32; i += 8)
        t[ly + i][lx] = W[(size_t)(k0 + ly + i) * TOTAL_DIM + d0 + lx];
    __syncthreads();
    #pragma unroll
    for (int i = 0; i < 32; i += 8) {
        float v = t[lx][ly + i];              // = W[k0+lx][d0+ly+i]
        bfp s = split2(v);
        size_t o = (size_t)(d0 + ly + i) * HIDDEN + k0 + lx;
        wht[o] = s.hi; wlt[o] = s.lo; wt32[o] = v;
    }
}

// ------------- fused: bf16x3 MFMA GEMM (64x64, BK=64, XOR-swz LDS) + convert -------
#define GBM 64
#define GBN 64
#define GBK 64
#define GEMM_MB (8192 / GBM)                    // 128
#define GEMM_NB (TOTAL_DIM / GBN)               // 10
#define GEMM_BLKS (GEMM_MB * GEMM_NB)           // 1280
#define CONV_BLKS 1024
#define CPG 32                                  // cols per group
#define NGRP (OUTD / CPG)                       // 32

__global__ __launch_bounds__(256)
void gemm_convert(const float* __restrict__ x, const ushort* __restrict__ wht,
                  const ushort* __restrict__ wlt, const float* __restrict__ bproj,
                  float* __restrict__ z,
                  const float* __restrict__ tables, ushort* __restrict__ btab)
{
    __shared__ ushort Ah[GBM * GBK];
    __shared__ ushort Al[GBM * GBK];
    __shared__ ushort Bh[GBN * GBK];
    __shared__ ushort Bl[GBN * GBK];

    const int gb  = blockIdx.x;
    const int tid = threadIdx.x;

    if (gb >= GEMM_BLKS) {
        // ---- convert path: output-linear over btab ux4s ----
        const int cb = gb - GEMM_BLKS;                  // 0..1023
        const int nj = NUM_TABLE * TABLE_SZ * (OUTD / 4);   // 16.78M
        const fx4* tp = (const fx4*)tables;
        const int stride = CONV_BLKS * 256;
        for (int j = cb * 256 + tid; j < nj; j += stride) {
            int sub = j & 7;                            // 4-col piece within group
            int row = (j >> 3) & 1023;
            int t   = (j >> 13) & 63;
            int g   = j >> 19;                          // 0..31
            fx4 v = __builtin_nontemporal_load(
                        &tp[((size_t)t * TABLE_SZ + row) * 256 + g * 8 + sub]);
            ux4 u;
            u.x = f2bf(v.x); u.y = f2bf(v.y); u.z = f2bf(v.z); u.w = f2bf(v.w);
            *(ux4*)&btab[(size_t)j * 4] = u;            // fully coalesced
        }
        return;
    }

    // ---- GEMM path ----
    const int lane = tid & 63, wid = tid >> 6;
    const int wr = wid >> 1, wc = wid & 1;             // 2x2 wave grid (32x32 each)
    const int brow = (gb % GEMM_MB) * GBM;
    const int bcol = (gb / GEMM_MB) * GBN;
    const int fr = lane & 15, fq = lane >> 4;

    f32x4 acc[2][2] = {};

    for (int k0 = 0; k0 < HIDDEN; k0 += GBK) {
        // stage A: 64 rows x 64 k fp32 -> split -> swizzled ux8 chunks
        #pragma unroll
        for (int i = 0; i < 2; ++i) {
            int idx = tid + i * 256;                   // 0..511
            int r = idx >> 3, c8 = idx & 7;            // logical 16B chunk
            const float* xp = &x[(size_t)(brow + r) * HIDDEN + k0 + c8 * 8];
            fx4 v0 = *(const fx4*)xp;
            fx4 v1 = *(const fx4*)(xp + 4);
            bfp s0 = split2(v0.x), s1 = split2(v0.y), s2 = split2(v0.z), s3 = split2(v0.w);
            bfp s4 = split2(v1.x), s5 = split2(v1.y), s6 = split2(v1.z), s7 = split2(v1.w);
            ux8 h, l;
            h[0]=s0.hi; h[1]=s1.hi; h[2]=s2.hi; h[3]=s3.hi;
            h[4]=s4.hi; h[5]=s5.hi; h[6]=s6.hi; h[7]=s7.hi;
            l[0]=s0.lo; l[1]=s1.lo; l[2]=s2.lo; l[3]=s3.lo;
            l[4]=s4.lo; l[5]=s5.lo; l[6]=s6.lo; l[7]=s7.lo;
            int so = r * GBK + (c8 ^ (r & 7)) * 8;
            *(ux8*)&Ah[so] = h;
            *(ux8*)&Al[so] = l;
        }
        // stage B^T: 64 n x 64 k bf16, swizzled ux8 copies
        #pragma unroll
        for (int i = 0; i < 2; ++i) {
            int idx = tid + i * 256;
            int nr = idx >> 3, c8 = idx & 7;
            size_t o = (size_t)(bcol + nr) * HIDDEN + k0 + c8 * 8;
            int so = nr * GBK + (c8 ^ (nr & 7)) * 8;
            *(ux8*)&Bh[so] = *(const ux8*)&wht[o];
            *(ux8*)&Bl[so] = *(const ux8*)&wlt[o];
        }
        __syncthreads();

        #pragma unroll
        for (int kk = 0; kk < 2; ++kk) {               // two K=32 slices
            bf16x8 ah[2], al[2], bh[2], bl[2];
            #pragma unroll
            for (int m = 0; m < 2; ++m) {
                int r = wr * 32 + m * 16 + fr;
                int so = r * GBK + (((kk << 2) | fq) ^ (r & 7)) * 8;
                ah[m] = *(const bf16x8*)&Ah[so];
                al[m] = *(const bf16x8*)&Al[so];
            }
            #pragma unroll
            for (int n = 0; n < 2; ++n) {
                int r = wc * 32 + n * 16 + fr;
                int so = r * GBK + (((kk << 2) | fq) ^ (r & 7)) * 8;
                bh[n] = *(const bf16x8*)&Bh[so];
                bl[n] = *(const bf16x8*)&Bl[so];
            }
            #pragma unroll
            for (int m = 0; m < 2; ++m)
                #pragma unroll
                for (int n = 0; n < 2; ++n) {
                    acc[m][n] = __builtin_amdgcn_mfma_f32_16x16x32_bf16(ah[m], bh[n], acc[m][n], 0, 0, 0);
                    acc[m][n] = __builtin_amdgcn_mfma_f32_16x16x32_bf16(ah[m], bl[n], acc[m][n], 0, 0, 0);
                    acc[m][n] = __builtin_amdgcn_mfma_f32_16x16x32_bf16(al[m], bh[n], acc[m][n], 0, 0, 0);
                }
        }
        __syncthreads();
    }

    // epilogue: +bias; C/D mapping col=lane&15, row=(lane>>4)*4+reg  [m89]
    #pragma unroll
    for (int n = 0; n < 2; ++n) {
        int col = bcol + wc * 32 + n * 16 + fr;
        float bb = bproj[col];
        #pragma unroll
        for (int m = 0; m < 2; ++m) {
            int rbase = brow + wr * 32 + m * 16 + fq * 4;
            #pragma unroll
            for (int j = 0; j < 4; ++j)
                z[(size_t)(rbase + j) * TOTAL_DIM + col] = acc[m][n][j] + bb;
        }
    }
}

// ------- code / score + near-zero flagging (ballot-aggregated, sign in bit31) ----
__global__ __launch_bounds__(256)
void code_score2(const float* __restrict__ z, int* __restrict__ code,
                 float* __restrict__ score, uint32_t* __restrict__ flags,
                 uint32_t* __restrict__ cnt, int NT)
{
    int idx = blockIdx.x * 256 + threadIdx.x;
    bool live = idx < NT;
    int n = idx >> 6;
    int t = idx & 63;
    const int lane = threadIdx.x & 63;
    const float* zp = z + (size_t)n * TOTAL_DIM + t * CODE_LEN;
    float s = 1.0f;
    int   c = 0;
    #pragma unroll
    for (int i = 0; i < CODE_LEN; ++i) {
        float v = live ? zp[i] : 1.0f;
        bool  p = fabsf(v) < TAU;                   // sign uncertain under bf16x3
        unsigned long long mask = __ballot(p);
        if (mask) {                                 // one atomic per wave per i
            int nact = __popcll(mask);
            int lead = __ffsll((long long)mask) - 1;
            uint32_t base = 0;
            if (lane == lead) base = atomicAdd(cnt, (uint32_t)nact);
            base = (uint32_t)__shfl((int)base, lead);
            if (p) {
                uint32_t slot = base + (uint32_t)__popcll(mask & ((1ull << lane) - 1ull));
                if (slot < FCAP) {
                    uint32_t nd = (uint32_t)(n * TOTAL_DIM + t * CODE_LEN + i);
                    flags[slot] = nd | (v > 0.0f ? 0x80000000u : 0u);
                }
            }
        }
        s *= 0.5f * (1.0f + tanhf(fabsf(v)));
        c |= (v > 0.0f) ? (1 << i) : 0;
    }
    if (live) {
        code[idx]  = c;
        score[idx] = s;
    }
}

// ----- exact fp32 recompute of flagged z via transposed W (coalesced); fix bits ----
__global__ __launch_bounds__(256)
void fixz(const float* __restrict__ x, const float* __restrict__ wt32,
          const float* __restrict__ bproj, int* __restrict__ code,
          const uint32_t* __restrict__ flags, const uint32_t* __restrict__ cnt)
{
    const int lane = threadIdx.x & 63;
    const int gw   = (blockIdx.x * 256 + threadIdx.x) >> 6;
    const int nw   = (gridDim.x * 256) >> 6;
    uint32_t count = *cnt;
    if (count > FCAP) count = FCAP;

    for (uint32_t f = gw; f < count; f += nw) {
        uint32_t fl = flags[f];
        uint32_t e  = fl & 0x7FFFFFFFu;
        int oldpos  = (int)(fl >> 31);
        int n = e / TOTAL_DIM, d = e % TOTAL_DIM;
        const float* xr = x    + (size_t)n * HIDDEN;
        const float* wr = wt32 + (size_t)d * HIDDEN;
        float p = 0.0f;
        #pragma unroll
        for (int j = 0; j < 16; ++j) {
            int k = lane + j * 64;
            p = fmaf(xr[k], wr[k], p);
        }
        #pragma unroll
        for (int off = 32; off; off >>= 1) p += __shfl_xor(p, off);
        float v = p + bproj[d];
        if (lane == 0) {
            if ((v > 0.0f) != (oldpos != 0)) {
                int t = d / CODE_LEN, i = d % CODE_LEN;
                atomicXor(&code[n * NUM_TABLE + t], 1 << i);
            }
        }
    }
}

// ------ gather, column-grouped: block = 64 tokens x one 32-col group --------------
// code/score loads are REGULAR (L2/L3-cacheable: 4 MB source re-read 32x);
// out writes stay nontemporal (write-once). Table loop unroll 8 for MLP.
#define TPB 64
__global__ __launch_bounds__(256)
void gather_grouped(const ushort* __restrict__ btab, const float* __restrict__ bias,
                    const int* __restrict__ code, const float* __restrict__ score,
                    float* __restrict__ out)
{
    __shared__ int   sc[TPB][NUM_TABLE + 1];
    __shared__ float sw[TPB][NUM_TABLE + 1];

    const int b   = blockIdx.x;
    const int g   = (b & 7) + 8 * (b >> 10);     // 0..31, XCD-aligned phases
    const int tch = (b >> 3) & 127;              // 128 chunks of 64 tokens
    const int n0  = tch * TPB;
    const int tid = threadIdx.x;

    for (int i = tid; i < TPB * NUM_TABLE; i += 256) {
        int tok = i >> 6, t = i & 63;
        sc[tok][t] = code[(n0 + tok) * NUM_TABLE + t];
        sw[tok][t] = score[(n0 + tok) * NUM_TABLE + t];
    }
    __syncthreads();

    const int tok = tid >> 2;                    // 0..63
    const int sub = tid & 3;                     // 8 cols each (16 B)
    const ushort* tbase = btab + (size_t)g * NUM_TABLE * TABLE_SZ * CPG + sub * 8;

    float acc[8];
    {
        const float* bp = &bias[g * CPG + sub * 8];
        #pragma unroll
        for (int j = 0; j < 8; ++j) acc[j] = bp[j];
    }

    #pragma unroll 8
    for (int t = 0; t < NUM_TABLE; ++t) {
        int   c = sc[tok][t];
        float w = sw[tok][t];
        const ux8 v = *(const ux8*)&tbase[((size_t)t * TABLE_SZ + c) << 5];
        #pragma unroll
        for (int j = 0; j < 8; ++j)
            acc[j] += w * __uint_as_float((uint32_t)v[j] << 16);
    }

    fx4 o0 = {acc[0], acc[1], acc[2], acc[3]};
    fx4 o1 = {acc[4], acc[5], acc[6], acc[7]};
    float* op = &out[(size_t)(n0 + tok) * OUTD + g * CPG + sub * 8];
    __builtin_nontemporal_store(o0, (fx4*)op);
    __builtin_nontemporal_store(o1, (fx4*)(op + 4));
}

// ---------------- fallback path (ws too small): fp32 vector GEMM + f32 gather ----
#define BM 64
#define BN 64
#define BK 32
__global__ __launch_bounds__(256)
void gemm_proj(const float* __restrict__ x, const float* __restrict__ W,
               const float* __restrict__ bproj, float* __restrict__ z)
{
    __shared__ float As[BK][BM + 4];
    __shared__ float Bs[BK][BN];
    const int tid  = threadIdx.x;
    const int brow = blockIdx.x * BM;
    const int bcol = blockIdx.y * BN;
    const int tr   = tid >> 4;
    const int tc   = tid & 15;
    float acc[4][4] = {};
    for (int k0 = 0; k0 < HIDDEN; k0 += BK) {
        #pragma unroll
        for (int i = 0; i < 2; ++i) {
            int lin = tid + i * 256;
            int r = lin >> 3, c8 = lin & 7;
            float4 a = *(const float4*)&x[(size_t)(brow + r) * HIDDEN + k0 + c8 * 4];
            As[c8 * 4 + 0][r] = a.x; As[c8 * 4 + 1][r] = a.y;
            As[c8 * 4 + 2][r] = a.z; As[c8 * 4 + 3][r] = a.w;
        }
        #pragma unroll
        for (int i = 0; i < 2; ++i) {
            int lin = tid + i * 256;
            int kk = lin >> 4, m4 = lin & 15;
            *(float4*)&Bs[kk][m4 * 4] =
                *(const float4*)&W[(size_t)(k0 + kk) * TOTAL_DIM + bcol + m4 * 4];
        }
        __syncthreads();
        #pragma unroll
        for (int kk = 0; kk < BK; ++kk) {
            float4 a = *(const float4*)&As[kk][tr * 4];
            float4 b = *(const float4*)&Bs[kk][tc * 4];
            acc[0][0] += a.x * b.x; acc[0][1] += a.x * b.y; acc[0][2] += a.x * b.z; acc[0][3] += a.x * b.w;
            acc[1][0] += a.y * b.x; acc[1][1] += a.y * b.y; acc[1][2] += a.y * b.z; acc[1][3] += a.y * b.w;
            acc[2][0] += a.z * b.x; acc[2][1] += a.z * b.y; acc[2][2] += a.z * b.z; acc[2][3] += a.z * b.w;
            acc[3][0] += a.w * b.x; acc[3][1] += a.w * b.y; acc[3][2] += a.w * b.z; acc[3][3] += a.w * b.w;
        }
        __syncthreads();
    }
    float4 bb = *(const float4*)&bproj[bcol + tc * 4];
    #pragma unroll
    for (int i = 0; i < 4; ++i) {
        int r = brow + tr * 4 + i;
        float4 o = {acc[i][0] + bb.x, acc[i][1] + bb.y, acc[i][2] + bb.z, acc[i][3] + bb.w};
        *(float4*)&z[(size_t)r * TOTAL_DIM + bcol + tc * 4] = o;
    }
}

__global__ __launch_bounds__(256)
void code_score(const float* __restrict__ z, int* __restrict__ code,
                float* __restrict__ score, int NT)
{
    int idx = blockIdx.x * 256 + threadIdx.x;
    if (idx >= NT) return;
    int n = idx >> 6, t = idx & 63;
    const float* zp = z + (size_t)n * TOTAL_DIM + t * CODE_LEN;
    float s = 1.0f; int c = 0;
    #pragma unroll
    for (int i = 0; i < CODE_LEN; ++i) {
        float v = zp[i];
        s *= 0.5f * (1.0f + tanhf(fabsf(v)));
        c |= (v > 0.0f) ? (1 << i) : 0;
    }
    code[idx] = c; score[idx] = s;
}

__global__ __launch_bounds__(256)
void gather_sum_f32(const float* __restrict__ tables, const float* __restrict__ bias,
                    const int* __restrict__ code, const float* __restrict__ score,
                    float* __restrict__ out)
{
    __shared__ int   sc[NUM_TABLE];
    __shared__ float sw[NUM_TABLE];
    const int n = blockIdx.x, tid = threadIdx.x;
    if (tid < NUM_TABLE) {
        sc[tid] = code[n * NUM_TABLE + tid];
        sw[tid] = score[n * NUM_TABLE + tid];
    }
    __syncthreads();
    float4 acc = *(const float4*)&bias[tid * 4];
    #pragma unroll 4
    for (int t = 0; t < NUM_TABLE; ++t) {
        const float* row = tables + ((size_t)(t * TABLE_SZ + sc[t])) * OUTD;
        float4 v = *(const float4*)&row[tid * 4];
        float w = sw[t];
        acc.x += v.x * w; acc.y += v.y * w; acc.z += v.z * w; acc.w += v.w * w;
    }
    *(float4*)&out[(size_t)n * OUTD + tid * 4] = acc;
}

extern "C" void kernel_launch(void* const* d_in, const int* in_sizes, int n_in,
                              void* d_out, int out_size, void* d_ws, size_t ws_size,
                              hipStream_t stream) {
    const float* x      = (const float*)d_in[0];
    const float* W      = (const float*)d_in[1];
    const float* bproj  = (const float*)d_in[2];
    const float* tables = (const float*)d_in[3];
    const float* bias   = (const float*)d_in[4];
    float* out = (float*)d_out;

    const int N = in_sizes[0] / HIDDEN;           // 8192

    // ws: z | code | score | wht | wlt | wt32 | flags | cnt | btab
    char* ws = (char*)d_ws;
    size_t off_z     = 0;
    size_t off_code  = off_z     + (size_t)N * TOTAL_DIM * sizeof(float);
    size_t off_score = off_code  + (size_t)N * NUM_TABLE * sizeof(int);
    size_t off_wht   = off_score + (size_t)N * NUM_TABLE * sizeof(float);
    size_t off_wlt   = off_wht   + (size_t)TOTAL_DIM * HIDDEN * sizeof(ushort);
    size_t off_wt32  = off_wlt   + (size_t)TOTAL_DIM * HIDDEN * sizeof(ushort);
    size_t off_flags = off_wt32  + (size_t)TOTAL_DIM * HIDDEN * sizeof(float);
    size_t off_cnt   = off_flags + (size_t)FCAP * sizeof(uint32_t);
    size_t off_btab  = (off_cnt + 4 + 255) & ~(size_t)255;
    size_t tab_elems = (size_t)NUM_TABLE * TABLE_SZ * OUTD;
    size_t need      = off_btab + tab_elems * sizeof(ushort);

    float*    z     = (float*)(ws + off_z);
    int*      code  = (int*)(ws + off_code);
    float*    score = (float*)(ws + off_score);
    ushort*   wht   = (ushort*)(ws + off_wht);
    ushort*   wlt   = (ushort*)(ws + off_wlt);
    float*    wt32  = (float*)(ws + off_wt32);
    uint32_t* flags = (uint32_t*)(ws + off_flags);
    uint32_t* cnt   = (uint32_t*)(ws + off_cnt);
    ushort*   btab  = (ushort*)(ws + off_btab);

    int NT = N * NUM_TABLE;

    if (ws_size >= need) {
        dim3 gw(TOTAL_DIM / 32, HIDDEN / 32);
        split_wt<<<gw, 256, 0, stream>>>(W, wht, wlt, wt32);
        (void)hipMemsetAsync(cnt, 0, 4, stream);

        gemm_convert<<<GEMM_BLKS + CONV_BLKS, 256, 0, stream>>>(
            x, wht, wlt, bproj, z, tables, btab);

        code_score2<<<(NT + 255) / 256, 256, 0, stream>>>(z, code, score, flags, cnt, NT);
        fixz<<<1024, 256, 0, stream>>>(x, wt32, bproj, code, flags, cnt);

        gather_grouped<<<NGRP * (N / TPB), 256, 0, stream>>>(btab, bias, code, score, out);
    } else {
        dim3 g1(N / BM, TOTAL_DIM / BN);
        gemm_proj<<<g1, 256, 0, stream>>>(x, W, bproj, z);
        code_score<<<(NT + 255) / 256, 256, 0, stream>>>(z, code, score, NT);
        gather_sum_f32<<<N, 256, 0, stream>>>(tables, bias, code, score, out);
    }
}